// Round 19
// baseline (528.575 us; speedup 1.0000x reference)
//
#include <hip/hip_runtime.h>
#include <math.h>

#define ALPHA_LR 0.2f

#define Bq  32
#define Nq  128
#define Mq  1024
#define CDq 128
#define GDq 64
#define NHq 4
#define LDq 256
#define PDq 40

typedef unsigned short ushort_t;
typedef __attribute__((ext_vector_type(8))) short bf16x8;
typedef __attribute__((ext_vector_type(4))) float f32x4;

__device__ __forceinline__ ushort_t f2bf(float f) {
    union { float f; unsigned u; } x; x.f = f;
    unsigned r = x.u + 0x7FFFu + ((x.u >> 16) & 1u);   // RNE
    return (ushort_t)(r >> 16);
}
__device__ __forceinline__ float bf2f(ushort_t u) {
    union { unsigned u; float f; } x; x.u = ((unsigned)u) << 16;
    return x.f;
}
// fast tanh: 1 - 2*rcp(e^{2x}+1); saturation exact, rel err ~1e-6.
__device__ __forceinline__ float ftanh(float x) {
    float e = __expf(2.f * x);
    return 1.f - 2.f * __builtin_amdgcn_rcpf(e + 1.f);
}

// ---------------------------------------------------------------------------
// MFMA bf16 NT GEMM: C = act(A @ Bt^T + bias); OUTBF=1 writes bf16 directly
// ---------------------------------------------------------------------------
template<int ACT, int MASKED, int HAS_BIAS, int NT, int AF32, int OUTBF>
__global__ __launch_bounds__(256) void mfma_nt_k(
    int M, int N, int K, int Nout,
    const void* __restrict__ Av, int lda, long long sA,
    const ushort_t* __restrict__ Bt, int ldb, long long sB,
    const float* __restrict__ bias, long long sBias,
    void* __restrict__ Cv, int ldc, long long sC,
    const float* __restrict__ maskR, long long sW2,
    const float* __restrict__ maskC)
{
    int z = blockIdx.z;
    Bt += (long long)z * sB;
    if (HAS_BIAS) bias += (long long)z * sBias;
    float* C = nullptr; ushort_t* Cb = nullptr;
    if (OUTBF) Cb = (ushort_t*)Cv + (long long)z * sC;
    else       C  = (float*)Cv + (long long)z * sC;

    int wave = threadIdx.x >> 6;
    int lane = threadIdx.x & 63;
    int lr = lane & 15;
    int kg = lane >> 4;
    int m0 = (blockIdx.x * 4 + wave) * 16;
    int n0 = blockIdx.y * (NT * 16);
    if (m0 >= M) return;

    f32x4 acc[NT];
    #pragma unroll
    for (int t = 0; t < NT; t++) acc[t] = (f32x4){0.f, 0.f, 0.f, 0.f};

    const ushort_t* Ab = nullptr;
    const float*    Af = nullptr;
    if (AF32) Af = (const float*)Av + (long long)z * sA + (long long)(m0 + lr) * lda + kg * 8;
    else      Ab = (const ushort_t*)Av + (long long)z * sA + (long long)(m0 + lr) * lda + kg * 8;
    const ushort_t* Bbase = Bt + (long long)(n0 + lr) * ldb + kg * 8;

    for (int k0 = 0; k0 < K; k0 += 32) {
        bf16x8 a;
        if (AF32) {
            float4 a0 = *(const float4*)(Af + k0);
            float4 a1 = *(const float4*)(Af + k0 + 4);
            a[0] = (short)f2bf(a0.x); a[1] = (short)f2bf(a0.y);
            a[2] = (short)f2bf(a0.z); a[3] = (short)f2bf(a0.w);
            a[4] = (short)f2bf(a1.x); a[5] = (short)f2bf(a1.y);
            a[6] = (short)f2bf(a1.z); a[7] = (short)f2bf(a1.w);
        } else {
            a = *(const bf16x8*)(Ab + k0);
        }
        #pragma unroll
        for (int t = 0; t < NT; t++) {
            bf16x8 b = *(const bf16x8*)(Bbase + (long long)t * 16 * ldb + k0);
            acc[t] = __builtin_amdgcn_mfma_f32_16x16x32_bf16(a, b, acc[t], 0, 0, 0);
        }
    }

    int row0 = m0 + kg * 4;
    #pragma unroll
    for (int t = 0; t < NT; t++) {
        int col = n0 + t * 16 + lr;
        if (col >= Nout) continue;
        float bv = HAS_BIAS ? bias[col] : 0.f;
        float mC = MASKED ? maskC[(long long)z * N + col] : 1.f;
        #pragma unroll
        for (int r = 0; r < 4; r++) {
            float v = acc[t][r] + bv;
            if (ACT == 1) v = v > 0.f ? v : ALPHA_LR * v;
            else if (ACT == 2) v = ftanh(v);
            if (MASKED) v *= maskR[(long long)z * M + row0 + r] * mC;
            if (OUTBF) Cb[(long long)(row0 + r) * ldc + col] = f2bf(v);
            else       C[(long long)(row0 + r) * ldc + col] = v;
        }
    }
}

// ---------------------------------------------------------------------------
// dedicated pv0 GEMM (LDS-staged coalesced fp32 A)
// ---------------------------------------------------------------------------
__global__ __launch_bounds__(256) void pv0_k(
    const float* __restrict__ amino,      // [32768][1024]
    const ushort_t* __restrict__ Bt,      // [48][1024] bf16 (padded)
    const float* __restrict__ bias,       // [40]
    float* __restrict__ C)                // [32768][40]
{
    __shared__ float As[64][68];
    int tid = threadIdx.x;
    int wave = tid >> 6, lane = tid & 63;
    int lr = lane & 15, kg = lane >> 4;
    int m0 = blockIdx.x * 64;

    f32x4 acc[3];
    #pragma unroll
    for (int t = 0; t < 3; t++) acc[t] = (f32x4){0.f, 0.f, 0.f, 0.f};

    int srow = tid >> 2;
    int scol = (tid & 3) * 16;
    const float* srcbase = amino + (long long)(m0 + srow) * 1024 + scol;

    for (int k0 = 0; k0 < 1024; k0 += 64) {
        float4 v0 = *(const float4*)(srcbase + k0);
        float4 v1 = *(const float4*)(srcbase + k0 + 4);
        float4 v2 = *(const float4*)(srcbase + k0 + 8);
        float4 v3 = *(const float4*)(srcbase + k0 + 12);
        *(float4*)&As[srow][scol]      = v0;
        *(float4*)&As[srow][scol + 4]  = v1;
        *(float4*)&As[srow][scol + 8]  = v2;
        *(float4*)&As[srow][scol + 12] = v3;
        __syncthreads();
        #pragma unroll
        for (int ks = 0; ks < 2; ks++) {
            const float* ap = &As[wave * 16 + lr][ks * 32 + kg * 8];
            bf16x8 a;
            #pragma unroll
            for (int j = 0; j < 8; j++) a[j] = (short)f2bf(ap[j]);
            #pragma unroll
            for (int t = 0; t < 3; t++) {
                bf16x8 bfr = *(const bf16x8*)(Bt + (long long)(t * 16 + lr) * 1024 + k0 + ks * 32 + kg * 8);
                acc[t] = __builtin_amdgcn_mfma_f32_16x16x32_bf16(a, bfr, acc[t], 0, 0, 0);
            }
        }
        __syncthreads();
    }
    int row0 = m0 + wave * 16 + kg * 4;
    #pragma unroll
    for (int t = 0; t < 3; t++) {
        int col = t * 16 + lr;
        if (col >= PDq) continue;
        float bv = bias[col];
        #pragma unroll
        for (int r = 0; r < 4; r++)
            C[(long long)(row0 + r) * PDq + col] = acc[t][r] + bv;
    }
}

// ---------------------------------------------------------------------------
// r19: fused reduce GEMM, MT=4 row-tiles per staged weight tile (halves the
// per-MFMA weight-staging traffic vs r14's MT=2). Per-row sums unchanged.
// grid = (M/256, 1, Z). K == N == 256.
// ---------------------------------------------------------------------------
__global__ __launch_bounds__(256) void mfma_reduceF_k(
    int M,
    const ushort_t* __restrict__ A,
    const ushort_t* __restrict__ W8,
    const float* __restrict__ bias8,
    const float* __restrict__ w28,
    float* __restrict__ C)
{
    int z = blockIdx.z;
    const ushort_t* W = W8 + (long long)z * 65536;
    const float* bias = bias8 + z * 256;
    const float* w2   = w28 + z * 256;
    float* Cz = C + (long long)z * M;

    __shared__ ushort_t Bs[64 * 256];   // 32 KB

    int tid = threadIdx.x;
    int wave = tid >> 6, lane = tid & 63;
    int lr = lane & 15, kg = lane >> 4;
    int m0 = blockIdx.x * 256 + wave * 16;

    bf16x8 areg[4][8];
    #pragma unroll
    for (int t4 = 0; t4 < 4; t4++) {
        const ushort_t* Ab = A + (long long)(m0 + t4 * 64 + lr) * 256 + kg * 8;
        #pragma unroll
        for (int kb = 0; kb < 8; kb++)
            areg[t4][kb] = *(const bf16x8*)(Ab + kb * 32);
    }

    float rs[4][4] = {};

    for (int ph = 0; ph < 4; ph++) {
        int n0 = ph * 64;
        #pragma unroll
        for (int step = 0; step < 8; step++) {
            int g = step * 256 + tid;
            int row = g >> 5, slot = g & 31;
            uint4 v = *(const uint4*)(W + (long long)(n0 + row) * 256 + slot * 8);
            int dst = row * 512 + ((slot * 16) ^ ((row & 31) << 4));
            *(uint4*)((char*)Bs + dst) = v;
        }
        __syncthreads();

        #pragma unroll
        for (int t4 = 0; t4 < 4; t4++) {
            f32x4 acc[4];
            #pragma unroll
            for (int t = 0; t < 4; t++) acc[t] = (f32x4){0.f, 0.f, 0.f, 0.f};
            #pragma unroll
            for (int kb = 0; kb < 8; kb++) {
                #pragma unroll
                for (int t = 0; t < 4; t++) {
                    int rowl = t * 16 + lr;
                    int colb = (kg * 16 + kb * 64) ^ ((rowl & 31) << 4);
                    bf16x8 b = *(const bf16x8*)((char*)Bs + rowl * 512 + colb);
                    acc[t] = __builtin_amdgcn_mfma_f32_16x16x32_bf16(areg[t4][kb], b, acc[t], 0, 0, 0);
                }
            }
            #pragma unroll
            for (int t = 0; t < 4; t++) {
                int col = n0 + t * 16 + lr;
                float bv = bias[col], wv = w2[col];
                #pragma unroll
                for (int r = 0; r < 4; r++)
                    rs[t4][r] += ftanh(acc[t][r] + bv) * wv;
            }
        }
        __syncthreads();
    }

    #pragma unroll
    for (int t4 = 0; t4 < 4; t4++) {
        #pragma unroll
        for (int r = 0; r < 4; r++) {
            rs[t4][r] += __shfl_xor(rs[t4][r], 1, 64);
            rs[t4][r] += __shfl_xor(rs[t4][r], 2, 64);
            rs[t4][r] += __shfl_xor(rs[t4][r], 4, 64);
            rs[t4][r] += __shfl_xor(rs[t4][r], 8, 64);
        }
    }
    if (lr == 0) {
        int row0 = m0 + kg * 4;
        #pragma unroll
        for (int t4 = 0; t4 < 4; t4++)
            #pragma unroll
            for (int r = 0; r < 4; r++)
                Cz[row0 + t4 * 64 + r] = rs[t4][r];
    }
}

// pack biases and w2 vectors for z=8 fused reduce
__global__ __launch_bounds__(256) void pack8_k(
    const float* __restrict__ b1, const float* __restrict__ b2,
    const float* __restrict__ w1, int w1Off,
    const float* __restrict__ w2v, int w2Off,
    float* __restrict__ bias8, float* __restrict__ w28)
{
    int j = blockIdx.x * 256 + threadIdx.x;
    int slot = j >> 8, c = j & 255;
    bias8[j] = slot < 4 ? b1[slot * 256 + c] : b2[(slot - 4) * 256 + c];
    w28[j]   = slot < 4 ? w1[slot * 512 + w1Off + c] : w2v[(slot - 4) * 512 + w2Off + c];
}

// ---------------------------------------------------------------------------
// fused BIDAT A-chain, MT=4 m-tiles, avU in registers
// ---------------------------------------------------------------------------
__global__ __launch_bounds__(256) void bidat_fused_k(
    const ushort_t* __restrict__ avU_all,
    const ushort_t* __restrict__ pv_bf,
    const float* __restrict__ rbuf_all,
    const float* __restrict__ qbuf_all,
    const float* __restrict__ atoms_mask,
    const float* __restrict__ amino_mask,
    float* __restrict__ scoreCp,
    float* __restrict__ csump)
{
    int z = blockIdx.z;
    int i = z >> 5, b = z & 31;
    int gx = blockIdx.x;
    int gy = blockIdx.y;
    int wave = threadIdx.x >> 6;
    int lane = threadIdx.x & 63;
    int lr = lane & 15, kg = lane >> 4;

    int n0 = gx * 64 + wave * 16;
    const ushort_t* Ab = avU_all + ((long long)i * 4096 + (long long)b * 128 + n0 + lr) * 256 + kg * 8;
    bf16x8 areg[8];
    #pragma unroll
    for (int kb = 0; kb < 8; kb++) areg[kb] = *(const bf16x8*)(Ab + kb * 32);

    const float* rI = rbuf_all + (long long)i * 32768 + (long long)b * 1024;
    const float* qI = qbuf_all + (long long)i * 4096 + (long long)b * 128;
    const float* mR = atoms_mask + (long long)b * 128;
    const float* mC = amino_mask + (long long)b * 1024;

    float mRn[4], qn[4];
    #pragma unroll
    for (int r = 0; r < 4; r++) {
        int n = n0 + kg * 4 + r;
        mRn[r] = mR[n];
        qn[r]  = qI[n];
    }

    float sc[4] = {0.f, 0.f, 0.f, 0.f};
    __shared__ float cl[4][64];

    for (int mt = 0; mt < 4; mt++) {
        int m0 = (gy * 4 + mt) * 64;
        const ushort_t* Bb = pv_bf + ((long long)b * 1024 + m0 + lr) * 256 + kg * 8;

        f32x4 acc[4];
        #pragma unroll
        for (int t = 0; t < 4; t++) acc[t] = (f32x4){0.f, 0.f, 0.f, 0.f};
        #pragma unroll
        for (int kb = 0; kb < 8; kb++) {
            #pragma unroll
            for (int t = 0; t < 4; t++) {
                bf16x8 bfr = *(const bf16x8*)(Bb + (long long)t * 16 * 256 + kb * 32);
                acc[t] = __builtin_amdgcn_mfma_f32_16x16x32_bf16(areg[kb], bfr, acc[t], 0, 0, 0);
            }
        }

        float cs[4] = {0.f, 0.f, 0.f, 0.f};
        #pragma unroll
        for (int t = 0; t < 4; t++) {
            int m = m0 + t * 16 + lr;
            float mc = mC[m];
            float rv = rI[m];
            #pragma unroll
            for (int r = 0; r < 4; r++) {
                float a = ftanh(acc[t][r]) * mRn[r] * mc;
                sc[r] += a * rv;
                cs[t] += a * qn[r];
            }
        }
        #pragma unroll
        for (int t = 0; t < 4; t++) {
            cs[t] += __shfl_xor(cs[t], 16, 64);
            cs[t] += __shfl_xor(cs[t], 32, 64);
        }
        __syncthreads();
        if (kg == 0) {
            #pragma unroll
            for (int t = 0; t < 4; t++) cl[wave][t * 16 + lr] = cs[t];
        }
        __syncthreads();
        if (threadIdx.x < 64) {
            float s = cl[0][threadIdx.x] + cl[1][threadIdx.x]
                    + cl[2][threadIdx.x] + cl[3][threadIdx.x];
            csump[((long long)z * 2 + gx) * 1024 + m0 + threadIdx.x] = s;
        }
    }

    #pragma unroll
    for (int r = 0; r < 4; r++) {
        sc[r] += __shfl_xor(sc[r], 1, 64);
        sc[r] += __shfl_xor(sc[r], 2, 64);
        sc[r] += __shfl_xor(sc[r], 4, 64);
        sc[r] += __shfl_xor(sc[r], 8, 64);
    }
    if (lr == 0) {
        #pragma unroll
        for (int r = 0; r < 4; r++) {
            int n = gx * 64 + wave * 16 + kg * 4 + r;
            scoreCp[((long long)z * 4 + gy) * 128 + n] = sc[r];
        }
    }
}

// finishC + masked softmax fused
__global__ __launch_bounds__(128) void finishC_sm_k(
    const float* __restrict__ scoreCp, const float* __restrict__ hbdot_all,
    const float* __restrict__ battc_b, const float* __restrict__ mask,
    float* __restrict__ scoreC_all)
{
    int z = blockIdx.x;
    int i = z >> 5, b = z & 31;
    int n = threadIdx.x;
    __shared__ float red[128];
    float s = 0.f;
    #pragma unroll
    for (int gy = 0; gy < 4; gy++)
        s += scoreCp[((long long)z * 4 + gy) * 128 + n];
    s += hbdot_all[(long long)i * 4096 + b * 128 + n] + battc_b[i];
    red[n] = s; __syncthreads();
    for (int off = 64; off > 0; off >>= 1) {
        if (n < off) red[n] = fmaxf(red[n], red[n + off]);
        __syncthreads();
    }
    float mx = red[0];
    __syncthreads();
    float e = __expf(s - mx) * mask[(long long)b * 128 + n];
    red[n] = e; __syncthreads();
    for (int off = 64; off > 0; off >>= 1) {
        if (n < off) red[n] += red[n + off];
        __syncthreads();
    }
    float inv = 1.0f / (red[0] + 1e-6f);
    scoreC_all[(long long)z * 128 + n] = e * inv;
}

// finishP + masked softmax fused
__global__ __launch_bounds__(256) void finishP_sm_k(
    const float* __restrict__ csump, const float* __restrict__ hpbdot_all,
    const float* __restrict__ battp_b, const float* __restrict__ mask,
    float* __restrict__ scoreP_all)
{
    int z = blockIdx.x;
    int i = z >> 5, b = z & 31;
    int t = threadIdx.x;
    __shared__ float red[256];
    float vals[4];
    float mx = -1e30f;
    #pragma unroll
    for (int j = 0; j < 4; j++) {
        int m = j * 256 + t;
        float s = csump[((long long)z * 2 + 0) * 1024 + m]
                + csump[((long long)z * 2 + 1) * 1024 + m]
                + hpbdot_all[(long long)i * 32768 + (long long)b * 1024 + m]
                + battp_b[i];
        vals[j] = s;
        mx = fmaxf(mx, s);
    }
    red[t] = mx; __syncthreads();
    for (int off = 128; off > 0; off >>= 1) {
        if (t < off) red[t] = fmaxf(red[t], red[t + off]);
        __syncthreads();
    }
    mx = red[0];
    __syncthreads();
    float sum = 0.f;
    #pragma unroll
    for (int j = 0; j < 4; j++) {
        float e = __expf(vals[j] - mx) * mask[(long long)b * 1024 + j * 256 + t];
        vals[j] = e; sum += e;
    }
    red[t] = sum; __syncthreads();
    for (int off = 128; off > 0; off >>= 1) {
        if (t < off) red[t] += red[t + off];
        __syncthreads();
    }
    float inv = 1.0f / (red[0] + 1e-6f);
    #pragma unroll
    for (int j = 0; j < 4; j++)
        scoreP_all[(long long)z * 1024 + j * 256 + t] = vals[j] * inv;
}

// fp32 [rows][Ksrc] -> bf16 [rows][Kdst] zero-padded (atoms_emb only)
__global__ __launch_bounds__(256) void cvtpad_bf16_k(
    const float* __restrict__ in, ushort_t* __restrict__ out,
    int rows, int Ksrc, int Kdst)
{
    long long idx = (long long)blockIdx.x * 256 + threadIdx.x;
    long long total = (long long)rows * Kdst;
    if (idx >= total) return;
    int r = (int)(idx / Kdst), k = (int)(idx % Kdst);
    out[idx] = (k < Ksrc) ? f2bf(in[(long long)r * Ksrc + k]) : (ushort_t)0;
}

// ---------------------------------------------------------------------------
// all weight transpose-converts in one table-driven launch
// ---------------------------------------------------------------------------
struct WtEnt {
    const float* W; ushort_t* Wt;
    int K, Nsrc, Npad, Kp, zcnt, blkStart;
};
struct WtTab { WtEnt e[11]; };

__global__ __launch_bounds__(256) void wtcvtAll_k(WtTab tab)
{
    int blk = blockIdx.x;
    int ei = 0;
    #pragma unroll
    for (int i = 1; i < 11; i++) if (blk >= tab.e[i].blkStart) ei = i;
    WtEnt E = tab.e[ei];
    long long perZ = (long long)E.Npad * E.Kp;
    long long lidx = (long long)(blk - E.blkStart) * 256 + threadIdx.x;
    if (lidx >= perZ * E.zcnt) return;
    int z = (int)(lidx / perZ);
    long long idx = lidx % perZ;
    int n = (int)(idx / E.Kp), k = (int)(idx % E.Kp);
    const float* Wz = E.W + (long long)z * E.K * E.Nsrc;
    ushort_t* Oz = E.Wt + (long long)z * perZ;
    float v = (k < E.K && n < E.Nsrc) ? Wz[(long long)k * E.Nsrc + n] : 0.f;
    Oz[idx] = f2bf(v);
}

// per-row GAT source/dest attention logits
__global__ __launch_bounds__(128) void gat_e_k(
    const float* __restrict__ Wh, int ldWh, int GD,
    const float* __restrict__ a, int aStride,
    float* __restrict__ esrc, float* __restrict__ edst, int rows)
{
    int row = blockIdx.x;
    int k = blockIdx.y;
    int g = threadIdx.x;
    float ws = 0.f, wd = 0.f;
    if (g < GD) {
        float wv = Wh[(long long)row * ldWh + k * GD + g];
        ws = wv * a[k * aStride + g];
        wd = wv * a[k * aStride + GD + g];
    }
    __shared__ float sb[2][128];
    sb[0][threadIdx.x] = ws; sb[1][threadIdx.x] = wd;
    __syncthreads();
    for (int off = 64; off > 0; off >>= 1) {
        if (threadIdx.x < off) {
            sb[0][threadIdx.x] += sb[0][threadIdx.x + off];
            sb[1][threadIdx.x] += sb[1][threadIdx.x + off];
        }
        __syncthreads();
    }
    if (threadIdx.x == 0) {
        esrc[(long long)k * rows + row] = sb[0][0];
        edst[(long long)k * rows + row] = sb[1][0];
    }
}

// ---------------------------------------------------------------------------
// GAT attention, 256-thread blocks, bf16 output
// ---------------------------------------------------------------------------
template<int GD>
__global__ __launch_bounds__(256) void gat_attn2_k(
    const float* __restrict__ Wh, int ldWh,
    const int* __restrict__ adj,
    const float* __restrict__ esrc, const float* __restrict__ edst,
    ushort_t* __restrict__ outp, int ldOut)
{
    int row = blockIdx.x;          // b*N + n
    int k = blockIdx.y;
    int rows = gridDim.x;
    int b = row >> 7, n = row & 127;
    int tid = threadIdx.x;

    __shared__ float att[128];
    __shared__ float red[128];
    __shared__ float sred[256];

    if (tid < 128) {
        float e = esrc[(long long)k * rows + row] + edst[(long long)k * rows + b * 128 + tid];
        e = e > 0.f ? e : ALPHA_LR * e;
        if (adj[(long long)b * 16384 + n * 128 + tid] <= 0) e = -9.0e15f;
        att[tid] = e;
        red[tid] = e;
    }
    __syncthreads();
    for (int off = 64; off > 0; off >>= 1) {
        if (tid < off) red[tid] = fmaxf(red[tid], red[tid + off]);
        __syncthreads();
    }
    float mx = red[0];
    __syncthreads();
    if (tid < 128) {
        float ex = __expf(att[tid] - mx);
        att[tid] = ex;
        red[tid] = ex;
    }
    __syncthreads();
    for (int off = 64; off > 0; off >>= 1) {
        if (tid < off) red[tid] += red[tid + off];
        __syncthreads();
    }
    float inv = 1.0f / red[0];
    __syncthreads();

    constexpr int SPLIT = 256 / GD;
    constexpr int CH = 128 / SPLIT;
    int g = tid % GD;
    int part = tid / GD;
    const float* Whb = Wh + (long long)(b * 128) * ldWh + k * GD + g;
    float s = 0.f;
    int mm0 = part * CH;
    for (int mm = mm0; mm < mm0 + CH; mm++)
        s += att[mm] * Whb[(long long)mm * ldWh];
    sred[part * GD + g] = s;
    __syncthreads();
    if (part == 0) {
        float tot = s;
        #pragma unroll
        for (int p = 1; p < SPLIT; p++) tot += sred[p * GD + g];
        tot *= inv;
        tot = tot > 0.f ? tot : expm1f(tot);   // ELU
        outp[(long long)row * ldOut + k * GD + g] = f2bf(tot);
    }
}

// ---------------------------------------------------------------------------
// fused 3x 11x11 conv chain, fully LDS-resident
// ---------------------------------------------------------------------------
__global__ __launch_bounds__(256) void conv3_k(
    const float* __restrict__ x,        // [32][1024][40] (pv0 out)
    const float* __restrict__ Wc,       // [3][121]
    const float* __restrict__ bc,       // [3]
    ushort_t* __restrict__ y)           // [32768][64] bf16, d>=40 zero
{
    __shared__ float wsh[3][121];
    __shared__ float A[94][50];
    __shared__ float Bv[84][50];
    __shared__ float Cv[74][50];

    int tid = threadIdx.x;
    int b = blockIdx.y;
    int m0 = blockIdx.x * 64;

    for (int i = tid; i < 363; i += 256) wsh[i / 121][i % 121] = Wc[i];
    const float* xb = x + (long long)b * Mq * PDq;
    for (int idx = tid; idx < 94 * 50; idx += 256) {
        int row = idx / 50, col = idx % 50;
        int gm = m0 - 15 + row, d = col - 5;
        float v = 0.f;
        if (d >= 0 && d < PDq && gm >= 0 && gm < Mq)
            v = xb[(long long)gm * PDq + d];
        A[row][col] = v;
    }
    __syncthreads();

    {
        float b0 = bc[0];
        for (int idx = tid; idx < 84 * 50; idx += 256) {
            int row = idx / 50, col = idx % 50;
            float s = 0.f;
            if (col >= 5 && col < 45) {
                int d = col - 5;
                #pragma unroll
                for (int i = 0; i < 11; i++)
                    #pragma unroll
                    for (int j = 0; j < 11; j++)
                        s += A[row + i][d + j] * wsh[0][i * 11 + j];
                s += b0;
                s = s > 0.f ? s : ALPHA_LR * s;
            }
            Bv[row][col] = s;
        }
    }
    __syncthreads();

    {
        float b1 = bc[1];
        for (int idx = tid; idx < 74 * 50; idx += 256) {
            int row = idx / 50, col = idx % 50;
            float s = 0.f;
            if (col >= 5 && col < 45) {
                int d = col - 5;
                #pragma unroll
                for (int i = 0; i < 11; i++)
                    #pragma unroll
                    for (int j = 0; j < 11; j++)
                        s += Bv[row + i][d + j] * wsh[1][i * 11 + j];
                s += b1;
                s = s > 0.f ? s : ALPHA_LR * s;
            }
            Cv[row][col] = s;
        }
    }
    __syncthreads();

    {
        float b2 = bc[2];
        for (int idx = tid; idx < 64 * 64; idx += 256) {
            int row = idx / 64, d = idx % 64;
            long long o = ((long long)b * Mq + m0 + row) * 64 + d;
            if (d >= PDq) { y[o] = 0; continue; }
            float s = 0.f;
            #pragma unroll
            for (int i = 0; i < 11; i++)
                #pragma unroll
                for (int j = 0; j < 11; j++)
                    s += Cv[row + i][d + j] * wsh[2][i * 11 + j];
            s += b2;
            s = s > 0.f ? s : ALPHA_LR * s;
            y[o] = f2bf(s);
        }
    }
}

// weighted sum stage 1 for ALL 4 i per feat read
__global__ __launch_bounds__(256) void wsum1B4_k(
    const ushort_t* __restrict__ feat, const float* __restrict__ att_all,
    float* __restrict__ partial, int L)
{
    int b = blockIdx.x, c = blockIdx.y, l = threadIdx.x;
    int chunk = L / 16;
    const ushort_t* fb = feat + (long long)b * L * LDq;
    const float* a0 = att_all + ((long long)0 * Bq + b) * L;
    const float* a1 = att_all + ((long long)1 * Bq + b) * L;
    const float* a2 = att_all + ((long long)2 * Bq + b) * L;
    const float* a3 = att_all + ((long long)3 * Bq + b) * L;
    float s0 = 0.f, s1 = 0.f, s2 = 0.f, s3 = 0.f;
    int r0 = c * chunk, r1 = r0 + chunk;
    for (int r = r0; r < r1; r++) {
        float f = bf2f(fb[(long long)r * LDq + l]);
        s0 += f * a0[r]; s1 += f * a1[r];
        s2 += f * a2[r]; s3 += f * a3[r];
    }
    partial[(((long long)0 * Bq + b) * 16 + c) * LDq + l] = s0;
    partial[(((long long)1 * Bq + b) * 16 + c) * LDq + l] = s1;
    partial[(((long long)2 * Bq + b) * 16 + c) * LDq + l] = s2;
    partial[(((long long)3 * Bq + b) * 16 + c) * LDq + l] = s3;
}

// ---------------------------------------------------------------------------
// r19: head layer reading wsum partials directly (kills wsum2B + cf/pf).
// vin element j (0..1023) of batch b = sum_{c=0..15} partial[((j/256)*Bq+b)*16+c)*256 + j%256]
// (same c-order as old wsum2B -> bit-identical)
// ---------------------------------------------------------------------------
__global__ __launch_bounds__(256) void headlinP_k(
    const float* __restrict__ partial,
    const float* __restrict__ W, int ldw,
    const float* __restrict__ bias,
    float* __restrict__ vout, int ldo, int OD, int colBase)
{
    int b = blockIdx.x;
    int c = threadIdx.x & 63;
    int s = threadIdx.x >> 6;
    int col = blockIdx.y * 64 + c;

    __shared__ float vs[1024];
    for (int j = threadIdx.x; j < 1024; j += 256) {
        int i = j >> 8, l = j & 255;
        const float* pbase = partial + (((long long)i * Bq + b) * 16) * LDq + l;
        float acc = 0.f;
        #pragma unroll
        for (int cc = 0; cc < 16; cc++) acc += pbase[cc * LDq];
        vs[j] = acc;
    }
    __syncthreads();

    float sum = 0.f;
    if (col < OD) {
        int k0 = 256 * s, k1 = 256 * (s + 1);
        #pragma unroll 4
        for (int k = k0; k < k1; k++)
            sum += vs[k] * W[(long long)k * ldw + col];
    }
    __shared__ float red[4][64];
    red[s][c] = sum;
    __syncthreads();
    if (s == 0 && col < OD) {
        float t = red[0][c] + red[1][c] + red[2][c] + red[3][c] + bias[col];
        vout[(long long)b * ldo + colBase + col] = t;
    }
}

// Skinny dense layer for the head (fp32 vin)
template<int ACT>
__global__ __launch_bounds__(256) void headlin_k(
    const float* __restrict__ vin, int ldv, int VD,
    const float* __restrict__ W, int ldw,
    const float* __restrict__ bias,
    float* __restrict__ vout, int ldo, int OD, int colBase)
{
    int b = blockIdx.x;
    int c = threadIdx.x & 63;
    int s = threadIdx.x >> 6;
    int col = blockIdx.y * 64 + c;

    __shared__ float vs[1024];
    for (int i = threadIdx.x; i < VD; i += 256) vs[i] = vin[(long long)b * ldv + i];
    __syncthreads();

    float sum = 0.f;
    if (col < OD) {
        int k0 = (VD * s) >> 2, k1 = (VD * (s + 1)) >> 2;
        #pragma unroll 4
        for (int k = k0; k < k1; k++)
            sum += vs[k] * W[(long long)k * ldw + col];
    }
    __shared__ float red[4][64];
    red[s][c] = sum;
    __syncthreads();
    if (s == 0 && col < OD) {
        float t = red[0][c] + red[1][c] + red[2][c] + red[3][c] + bias[col];
        if (ACT == 1) t = t > 0.f ? t : ALPHA_LR * t;
        vout[(long long)b * ldo + colBase + col] = t;
    }
}

// v[b,256:512]=fps, v[b,768]=invT, v[b,769]=T
__global__ __launch_bounds__(256) void vfill_k(
    const float* __restrict__ fps, const float* __restrict__ invT,
    const float* __restrict__ T, float* __restrict__ v)
{
    int b = blockIdx.x, t = threadIdx.x;
    v[(long long)b * 770 + 256 + t] = fps[(long long)b * 256 + t];
    if (t == 0) {
        v[(long long)b * 770 + 768] = invT[b];
        v[(long long)b * 770 + 769] = T[b];
    }
}

// out[b] = v[b,:770]·W + b
__global__ __launch_bounds__(256) void final_k(
    const float* __restrict__ v, const float* __restrict__ W,
    const float* __restrict__ bptr, float* __restrict__ out)
{
    int b = blockIdx.x, t = threadIdx.x;
    float s = 0.f;
    for (int i = t; i < 770; i += 256) s += v[(long long)b * 770 + i] * W[i];
    __shared__ float red[256];
    red[t] = s; __syncthreads();
    for (int off = 128; off > 0; off >>= 1) {
        if (t < off) red[t] += red[t + off];
        __syncthreads();
    }
    if (t == 0) out[b] = red[0] + bptr[0];
}

extern "C" void kernel_launch(void* const* d_in, const int* in_sizes, int n_in,
                              void* d_out, int out_size, void* d_ws, size_t ws_size,
                              hipStream_t stream)
{
    const float* atoms_emb = (const float*)d_in[0];
    const int*   adjacency = (const int*)d_in[1];
    const float* atoms_mask= (const float*)d_in[2];
    const float* amino_emb = (const float*)d_in[3];
    const float* amino_mask= (const float*)d_in[4];
    const float* fps       = (const float*)d_in[5];
    const float* inv_Temp  = (const float*)d_in[6];
    const float* Temp      = (const float*)d_in[7];
    const float* bert_W    = (const float*)d_in[8];
    const float* bert_b    = (const float*)d_in[9];
    const float* gat_W     = (const float*)d_in[10];
    const float* gat_a     = (const float*)d_in[11];
    const float* gatout_W  = (const float*)d_in[12];
    const float* gatout_a  = (const float*)d_in[13];
    const float* Wcomp_W   = (const float*)d_in[14];
    const float* Wcomp_b   = (const float*)d_in[15];
    const float* prot_W    = (const float*)d_in[16];
    const float* prot_b    = (const float*)d_in[17];
    const float* conv_W    = (const float*)d_in[18];
    const float* conv_b    = (const float*)d_in[19];
    const float* Wprot_W   = (const float*)d_in[20];
    const float* Wprot_b   = (const float*)d_in[21];
    const float* U         = (const float*)d_in[22];
    const float* tc2p_W    = (const float*)d_in[23];
    const float* tc2p_b    = (const float*)d_in[24];
    const float* tp2c_W    = (const float*)d_in[25];
    const float* tp2c_b    = (const float*)d_in[26];
    const float* bhc_W     = (const float*)d_in[27];
    const float* bhc_b     = (const float*)d_in[28];
    const float* bhp_W     = (const float*)d_in[29];
    const float* bhp_b     = (const float*)d_in[30];
    const float* battc_W   = (const float*)d_in[31];
    const float* battc_b   = (const float*)d_in[32];
    const float* battp_W   = (const float*)d_in[33];
    const float* battp_b   = (const float*)d_in[34];
    const float* combc_W   = (const float*)d_in[35];
    const float* combc_b   = (const float*)d_in[36];
    const float* combp_W   = (const float*)d_in[37];
    const float* combp_b   = (const float*)d_in[38];
    const float* Wout_W    = (const float*)d_in[39];
    const float* Wout_b    = (const float*)d_in[40];
    const float* out_W     = (const float*)d_in[41];
    const float* out_b     = (const float*)d_in[42];
    float* out = (float*)d_out;

    // ---- workspace layout (floats) ----
    float* w = (float*)d_ws;
    float* av    = w; w += (long long)Bq*Nq*LDq;
    float* pv    = w; w += (long long)Bq*Mq*LDq;
    float* sx    = w; w += (long long)Bq*Mq*LDq;   // early fp32 scratch -> precomp pool
    float* pool  = w; w += (long long)Bq*Nq*Mq;    // early bf16 staging -> partials
    float* bufU  = w; w += (long long)Bq*Nq*LDq;   // wsum partials (P side)
    float* bufTC = w; w += (long long)Bq*Nq*LDq;   // wsum partials (C side)
    float* esrc  = w; w += (long long)NHq*Bq*Nq;
    float* edst  = w; w += (long long)NHq*Bq*Nq;
    float* scoreC= w; w += (long long)Bq*Nq;
    float* scoreP= w; w += (long long)Bq*Mq;
    float* rbuf  = w; w += (long long)Bq*Mq;       // -> pack8 outputs
    float* qbuf  = w; w += (long long)Bq*Nq;
    float* csum  = w; w += (long long)Bq*Mq;
    float* cf    = w; w += (long long)Bq*4*LDq;
    float* pf    = w; w += (long long)Bq*4*LDq;
    float* v1    = w; w += (long long)Bq*770;
    float* v2    = w; w += (long long)Bq*770;
    // bf16 buffers
    ushort_t* pv_bf  = (ushort_t*)w; w += (long long)Bq*Mq*LDq/2;
    ushort_t* av_bf  = (ushort_t*)w; w += (long long)Bq*Nq*LDq/2;
    ushort_t* avU_bf = (ushort_t*)w; w += (long long)Bq*Nq*LDq/2;
    ushort_t* Ut_bf     = (ushort_t*)w; w += (long long)4*LDq*LDq/2;
    ushort_t* protWt_bf = (ushort_t*)w; w += (long long)48*1024/2;
    ushort_t* bertWt_bf = (ushort_t*)w; w += (long long)128*320/2;
    ushort_t* gatWt_bf  = (ushort_t*)w; w += (long long)4*64*128/2;
    ushort_t* gatoutWt_bf=(ushort_t*)w; w += (long long)128*256/2;
    ushort_t* WcompT_bf = (ushort_t*)w; w += (long long)256*128/2;
    ushort_t* WprotT_bf = (ushort_t*)w; w += (long long)256*64/2;
    ushort_t* wP_bf     = (ushort_t*)w; w += (long long)8*256*256/2;
    ushort_t* wA_bf     = (ushort_t*)w; w += (long long)8*256*256/2;

    int rowsA = Bq * Nq;     // 4096
    int rowsP = Bq * Mq;     // 32768

    // early fp32 aliases inside sx (dead before BIDAT precompute)
    float* h     = sx;
    float* WhAll = h + (long long)rowsA*CDq;
    float* multi = WhAll + (long long)rowsA*NHq*GDq;
    float* Wh2   = multi + (long long)rowsA*NHq*GDq;
    float* avp   = Wh2 + (long long)rowsA*CDq;
    float* c0    = avp + (long long)rowsA*CDq;
    float* c1    = c0 + (long long)rowsP*PDq;

    // early bf16 aliases inside pool (dead before partials phase)
    ushort_t* atoms_bf = (ushort_t*)pool;
    ushort_t* h_bf     = atoms_bf + (long long)rowsA*320;
    ushort_t* multi_bf = h_bf + (long long)rowsA*128;
    ushort_t* avp_bf   = multi_bf + (long long)rowsA*256;
    ushort_t* c1_bf    = avp_bf + (long long)rowsA*128;

    // BIDAT-precompute pool in sx (z=8 reduce outputs land contiguously)
    float*    rbuf_all   = sx;
    float*    hpbdot_all = rbuf_all   + (long long)4*rowsP;
    float*    qbuf_all   = hpbdot_all + (long long)4*rowsP;
    float*    hbdot_all  = qbuf_all   + (long long)4*rowsA;
    float*    bufU_all   = hbdot_all  + (long long)4*rowsA;
    ushort_t* avU_all_bf = (ushort_t*)(bufU_all + (long long)4*rowsA*LDq);

    // partials pool (after bidat)
    float* scoreCp    = pool;                        // 128*4*128
    float* csump      = scoreCp + 65536;             // 128*2*1024
    float* scoreC_all = csump + 262144;              // 16384
    float* scoreP_all = scoreC_all + 16384;          // 131072

    float* wpartC = bufTC;   // C-side wsum partials (4*32*16*256)
    float* wpartP = bufU;    // P-side wsum partials

    // pack8 outputs
    float* bias8P = rbuf;
    float* w28P   = rbuf + 2048;
    float* bias8A = rbuf + 4096;
    float* w28A   = rbuf + 6144;

    // ---- single table-driven weight convert launch ----
    WtTab tab;
    int blk = 0;
    auto setent = [&](int i, const float* W, ushort_t* Wt,
                      int K, int Nsrc, int Npad, int Kp, int zc) {
        tab.e[i].W = W; tab.e[i].Wt = Wt;
        tab.e[i].K = K; tab.e[i].Nsrc = Nsrc; tab.e[i].Npad = Npad;
        tab.e[i].Kp = Kp; tab.e[i].zcnt = zc; tab.e[i].blkStart = blk;
        blk += (int)(((long long)zc * Npad * Kp + 255) / 256);
    };
    setent(0,  U,        Ut_bf,       256, 256, 256, 256, 4);
    setent(1,  prot_W,   protWt_bf,   1024, 40, 48, 1024, 1);
    setent(2,  bert_W,   bertWt_bf,   300, 128, 128, 320, 1);
    setent(3,  gat_W,    gatWt_bf,    128, 64,  64,  128, 4);
    setent(4,  gatout_W, gatoutWt_bf, 256, 128, 128, 256, 1);
    setent(5,  Wcomp_W,  WcompT_bf,   128, 256, 256, 128, 1);
    setent(6,  Wprot_W,  WprotT_bf,   40,  256, 256, 64,  1);
    setent(7,  tp2c_W,   wP_bf,              256, 256, 256, 256, 4);
    setent(8,  bhp_W,    wP_bf + 4*65536,    256, 256, 256, 256, 4);
    setent(9,  tc2p_W,   wA_bf,              256, 256, 256, 256, 4);
    setent(10, bhc_W,    wA_bf + 4*65536,    256, 256, 256, 256, 4);
    wtcvtAll_k<<<blk, 256, 0, stream>>>(tab);
    pack8_k<<<8, 256, 0, stream>>>(tp2c_b, bhp_b, battc_W, 256, battp_W, 0, bias8P, w28P);
    pack8_k<<<8, 256, 0, stream>>>(tc2p_b, bhc_b, battp_W, 256, battc_W, 0, bias8A, w28A);

    // 1. h = atoms_emb @ bert_W + bert_b  (MFMA, K padded, bf16 out direct)
    cvtpad_bf16_k<<<(int)(((long long)rowsA*320 + 255)/256), 256, 0, stream>>>(
        atoms_emb, atoms_bf, rowsA, 300, 320);
    mfma_nt_k<0, 0, 1, 2, 0, 1><<<dim3(rowsA/64, 4, 1), 256, 0, stream>>>(
        rowsA, CDq, 320, CDq, (const void*)atoms_bf, 320, 0,
        bertWt_bf, 320, 0, bert_b, 0, (void*)h_bf, CDq, 0, nullptr, 0, nullptr);

    // 2. Wh_all = h @ gat_W[k]  (MFMA, z=4, fp32 out for gat_e)
    mfma_nt_k<0, 0, 0, 4, 0, 0><<<dim3(rowsA/64, 1, 4), 256, 0, stream>>>(
        rowsA, GDq, CDq, GDq, (const void*)h_bf, CDq, 0,
        gatWt_bf, CDq, (long long)GDq*CDq,
        nullptr, 0, (void*)WhAll, NHq*GDq, GDq, nullptr, 0, nullptr);

    // 3-4. GAT heads -> multi_bf (ELU, bf16 out direct)
    gat_e_k<<<dim3(rowsA, NHq), 128, 0, stream>>>(WhAll, NHq*GDq, GDq, gat_a, 2*GDq,
                                                  esrc, edst, rowsA);
    gat_attn2_k<64><<<dim3(rowsA, NHq), 256, 0, stream>>>(WhAll, NHq*GDq, adjacency,
                                                          esrc, edst, multi_bf, NHq*GDq);

    // 5-7. GAT out layer -> avp_bf (ELU)
    mfma_nt_k<0, 0, 0, 2, 0, 0><<<dim3(rowsA/64, 4, 1), 256, 0, stream>>>(
        rowsA, CDq, 256, CDq, (const void*)multi_bf, 256, 0,
        gatoutWt_bf, 256, 0, nullptr, 0, (void*)Wh2, CDq, 0, nullptr, 0, nullptr);
    gat_e_k<<<dim3(rowsA, 1), 128, 0, stream>>>(Wh2, CDq, CDq, gatout_a, 2*CDq,
                                                esrc, edst, rowsA);
    gat_attn2_k<128><<<dim3(rowsA, 1), 256, 0, stream>>>(Wh2, CDq, adjacency,
                                                         esrc, edst, avp_bf, CDq);

    // 8. av = leaky(avp @ Wcomp_W + b)  (MFMA, bf16 out direct)
    mfma_nt_k<1, 0, 1, 4, 0, 1><<<dim3(rowsA/64, 4, 1), 256, 0, stream>>>(
        rowsA, LDq, CDq, LDq, (const void*)avp_bf, CDq, 0,
        WcompT_bf, CDq, 0, Wcomp_b, 0, (void*)av_bf, LDq, 0, nullptr, 0, nullptr);

    // 9. pv0 = amino_emb @ prot_W + b  (LDS-staged coalesced kernel)
    pv0_k<<<rowsP/64, 256, 0, stream>>>(amino_emb, protWt_bf, prot_b, c0);

    // 10. fused 3x conv chain, LDS-resident, bf16 padded out
    conv3_k<<<dim3(Mq/64, Bq), 256, 0, stream>>>(c0, conv_W, conv_b, c1_bf);

    // 11. pv = leaky(x @ Wprot_W + b)  (MFMA, bf16 out direct)
    mfma_nt_k<1, 0, 1, 4, 0, 1><<<dim3(rowsP/64, 4, 1), 256, 0, stream>>>(
        rowsP, LDq, 64, LDq, (const void*)c1_bf, 64, 0,
        WprotT_bf, 64, 0, Wprot_b, 0, (void*)pv_bf, LDq, 0, nullptr, 0, nullptr);

    // ---- BIDAT precompute: fused z=8 reduces (r19: MT=4 row-tiles) ----
    mfma_reduceF_k<<<dim3(rowsP/256, 1, 8), 256, 0, stream>>>(
        rowsP, pv_bf, wP_bf, bias8P, w28P, rbuf_all);     // -> rbuf_all | hpbdot_all
    mfma_reduceF_k<<<dim3(rowsA/256, 1, 8), 256, 0, stream>>>(
        rowsA, av_bf, wA_bf, bias8A, w28A, qbuf_all);     // -> qbuf_all | hbdot_all
    // avU_all[i] = av @ U[i]  (bf16 out direct)
    mfma_nt_k<0, 0, 0, 4, 0, 1><<<dim3(rowsA/64, 4, 4), 256, 0, stream>>>(
        rowsA, LDq, LDq, LDq, (const void*)av_bf, LDq, 0,
        Ut_bf, LDq, (long long)LDq*LDq,
        nullptr, 0, (void*)avU_all_bf, LDq, (long long)rowsA*LDq,
        nullptr, 0, nullptr);

    // ---- fused BIDAT A-chain (MT=4 m-tiles, avU in registers) ----
    bidat_fused_k<<<dim3(2, 4, 128), 256, 0, stream>>>(
        avU_all_bf, pv_bf, rbuf_all, qbuf_all,
        atoms_mask, amino_mask, scoreCp, csump);
    finishC_sm_k<<<128, 128, 0, stream>>>(scoreCp, hbdot_all, battc_b,
                                          atoms_mask, scoreC_all);
    finishP_sm_k<<<128, 256, 0, stream>>>(csump, hpbdot_all, battp_b,
                                          amino_mask, scoreP_all);

    // pooled features (partials only; summation folded into headlinP)
    wsum1B4_k<<<dim3(Bq, 16), 256, 0, stream>>>(av_bf, scoreC_all, wpartC, Nq);
    wsum1B4_k<<<dim3(Bq, 16), 256, 0, stream>>>(pv_bf, scoreP_all, wpartP, Mq);

    // head (r19: headlinP reads partials directly)
    headlinP_k<<<dim3(Bq, 4), 256, 0, stream>>>(wpartC,
        combc_W, LDq, combc_b, v1, 770, LDq, 0);
    headlinP_k<<<dim3(Bq, 4), 256, 0, stream>>>(wpartP,
        combp_W, LDq, combp_b, v1, 770, LDq, 512);
    vfill_k<<<Bq, 256, 0, stream>>>(fps, inv_Temp, Temp, v1);

    headlin_k<1><<<dim3(Bq, 13), 256, 0, stream>>>(v1, 770, 770,
        Wout_W + 0ll*770*770, 770, Wout_b + 0*770, v2, 770, 770, 0);
    headlin_k<1><<<dim3(Bq, 13), 256, 0, stream>>>(v2, 770, 770,
        Wout_W + 1ll*770*770, 770, Wout_b + 1*770, v1, 770, 770, 0);
    headlin_k<1><<<dim3(Bq, 13), 256, 0, stream>>>(v1, 770, 770,
        Wout_W + 2ll*770*770, 770, Wout_b + 2*770, v2, 770, 770, 0);

    final_k<<<Bq, 256, 0, stream>>>(v2, out_W, out_b, out);

    (void)in_sizes; (void)n_in; (void)out_size; (void)ws_size;
    (void)av; (void)pv; (void)avU_bf; (void)qbuf; (void)csum;
    (void)scoreC; (void)scoreP; (void)h; (void)multi; (void)avp;
    (void)bufU_all; (void)c1; (void)cf; (void)pf;
}

// Round 21
// 513.282 us; speedup vs baseline: 1.0298x; 1.0298x over previous
//
#include <hip/hip_runtime.h>
#include <math.h>

#define ALPHA_LR 0.2f

#define Bq  32
#define Nq  128
#define Mq  1024
#define CDq 128
#define GDq 64
#define NHq 4
#define LDq 256
#define PDq 40

typedef unsigned short ushort_t;
typedef __attribute__((ext_vector_type(8))) short bf16x8;
typedef __attribute__((ext_vector_type(4))) float f32x4;

__device__ __forceinline__ ushort_t f2bf(float f) {
    union { float f; unsigned u; } x; x.f = f;
    unsigned r = x.u + 0x7FFFu + ((x.u >> 16) & 1u);   // RNE
    return (ushort_t)(r >> 16);
}
__device__ __forceinline__ float bf2f(ushort_t u) {
    union { unsigned u; float f; } x; x.u = ((unsigned)u) << 16;
    return x.f;
}
// fast tanh: 1 - 2*rcp(e^{2x}+1); saturation exact, rel err ~1e-6.
__device__ __forceinline__ float ftanh(float x) {
    float e = __expf(2.f * x);
    return 1.f - 2.f * __builtin_amdgcn_rcpf(e + 1.f);
}

// ---------------------------------------------------------------------------
// MFMA bf16 NT GEMM: C = act(A @ Bt^T + bias); OUTBF=1 writes bf16 directly
// ---------------------------------------------------------------------------
template<int ACT, int MASKED, int HAS_BIAS, int NT, int AF32, int OUTBF>
__global__ __launch_bounds__(256) void mfma_nt_k(
    int M, int N, int K, int Nout,
    const void* __restrict__ Av, int lda, long long sA,
    const ushort_t* __restrict__ Bt, int ldb, long long sB,
    const float* __restrict__ bias, long long sBias,
    void* __restrict__ Cv, int ldc, long long sC,
    const float* __restrict__ maskR, long long sW2,
    const float* __restrict__ maskC)
{
    int z = blockIdx.z;
    Bt += (long long)z * sB;
    if (HAS_BIAS) bias += (long long)z * sBias;
    float* C = nullptr; ushort_t* Cb = nullptr;
    if (OUTBF) Cb = (ushort_t*)Cv + (long long)z * sC;
    else       C  = (float*)Cv + (long long)z * sC;

    int wave = threadIdx.x >> 6;
    int lane = threadIdx.x & 63;
    int lr = lane & 15;
    int kg = lane >> 4;
    int m0 = (blockIdx.x * 4 + wave) * 16;
    int n0 = blockIdx.y * (NT * 16);
    if (m0 >= M) return;

    f32x4 acc[NT];
    #pragma unroll
    for (int t = 0; t < NT; t++) acc[t] = (f32x4){0.f, 0.f, 0.f, 0.f};

    const ushort_t* Ab = nullptr;
    const float*    Af = nullptr;
    if (AF32) Af = (const float*)Av + (long long)z * sA + (long long)(m0 + lr) * lda + kg * 8;
    else      Ab = (const ushort_t*)Av + (long long)z * sA + (long long)(m0 + lr) * lda + kg * 8;
    const ushort_t* Bbase = Bt + (long long)(n0 + lr) * ldb + kg * 8;

    for (int k0 = 0; k0 < K; k0 += 32) {
        bf16x8 a;
        if (AF32) {
            float4 a0 = *(const float4*)(Af + k0);
            float4 a1 = *(const float4*)(Af + k0 + 4);
            a[0] = (short)f2bf(a0.x); a[1] = (short)f2bf(a0.y);
            a[2] = (short)f2bf(a0.z); a[3] = (short)f2bf(a0.w);
            a[4] = (short)f2bf(a1.x); a[5] = (short)f2bf(a1.y);
            a[6] = (short)f2bf(a1.z); a[7] = (short)f2bf(a1.w);
        } else {
            a = *(const bf16x8*)(Ab + k0);
        }
        #pragma unroll
        for (int t = 0; t < NT; t++) {
            bf16x8 b = *(const bf16x8*)(Bbase + (long long)t * 16 * ldb + k0);
            acc[t] = __builtin_amdgcn_mfma_f32_16x16x32_bf16(a, b, acc[t], 0, 0, 0);
        }
    }

    int row0 = m0 + kg * 4;
    #pragma unroll
    for (int t = 0; t < NT; t++) {
        int col = n0 + t * 16 + lr;
        if (col >= Nout) continue;
        float bv = HAS_BIAS ? bias[col] : 0.f;
        float mC = MASKED ? maskC[(long long)z * N + col] : 1.f;
        #pragma unroll
        for (int r = 0; r < 4; r++) {
            float v = acc[t][r] + bv;
            if (ACT == 1) v = v > 0.f ? v : ALPHA_LR * v;
            else if (ACT == 2) v = ftanh(v);
            if (MASKED) v *= maskR[(long long)z * M + row0 + r] * mC;
            if (OUTBF) Cb[(long long)(row0 + r) * ldc + col] = f2bf(v);
            else       C[(long long)(row0 + r) * ldc + col] = v;
        }
    }
}

// ---------------------------------------------------------------------------
// dedicated pv0 GEMM (LDS-staged coalesced fp32 A)
// ---------------------------------------------------------------------------
__global__ __launch_bounds__(256) void pv0_k(
    const float* __restrict__ amino,      // [32768][1024]
    const ushort_t* __restrict__ Bt,      // [48][1024] bf16 (padded)
    const float* __restrict__ bias,       // [40]
    float* __restrict__ C)                // [32768][40]
{
    __shared__ float As[64][68];
    int tid = threadIdx.x;
    int wave = tid >> 6, lane = tid & 63;
    int lr = lane & 15, kg = lane >> 4;
    int m0 = blockIdx.x * 64;

    f32x4 acc[3];
    #pragma unroll
    for (int t = 0; t < 3; t++) acc[t] = (f32x4){0.f, 0.f, 0.f, 0.f};

    int srow = tid >> 2;
    int scol = (tid & 3) * 16;
    const float* srcbase = amino + (long long)(m0 + srow) * 1024 + scol;

    for (int k0 = 0; k0 < 1024; k0 += 64) {
        float4 v0 = *(const float4*)(srcbase + k0);
        float4 v1 = *(const float4*)(srcbase + k0 + 4);
        float4 v2 = *(const float4*)(srcbase + k0 + 8);
        float4 v3 = *(const float4*)(srcbase + k0 + 12);
        *(float4*)&As[srow][scol]      = v0;
        *(float4*)&As[srow][scol + 4]  = v1;
        *(float4*)&As[srow][scol + 8]  = v2;
        *(float4*)&As[srow][scol + 12] = v3;
        __syncthreads();
        #pragma unroll
        for (int ks = 0; ks < 2; ks++) {
            const float* ap = &As[wave * 16 + lr][ks * 32 + kg * 8];
            bf16x8 a;
            #pragma unroll
            for (int j = 0; j < 8; j++) a[j] = (short)f2bf(ap[j]);
            #pragma unroll
            for (int t = 0; t < 3; t++) {
                bf16x8 bfr = *(const bf16x8*)(Bt + (long long)(t * 16 + lr) * 1024 + k0 + ks * 32 + kg * 8);
                acc[t] = __builtin_amdgcn_mfma_f32_16x16x32_bf16(a, bfr, acc[t], 0, 0, 0);
            }
        }
        __syncthreads();
    }
    int row0 = m0 + wave * 16 + kg * 4;
    #pragma unroll
    for (int t = 0; t < 3; t++) {
        int col = t * 16 + lr;
        if (col >= PDq) continue;
        float bv = bias[col];
        #pragma unroll
        for (int r = 0; r < 4; r++)
            C[(long long)(row0 + r) * PDq + col] = acc[t][r] + bv;
    }
}

// ---------------------------------------------------------------------------
// fused reduce GEMM, MT=2 row-tiles per staged weight tile
// ---------------------------------------------------------------------------
__global__ __launch_bounds__(256) void mfma_reduceF_k(
    int M,
    const ushort_t* __restrict__ A,
    const ushort_t* __restrict__ W8,
    const float* __restrict__ bias8,
    const float* __restrict__ w28,
    float* __restrict__ C)
{
    int z = blockIdx.z;
    const ushort_t* W = W8 + (long long)z * 65536;
    const float* bias = bias8 + z * 256;
    const float* w2   = w28 + z * 256;
    float* Cz = C + (long long)z * M;

    __shared__ ushort_t Bs[64 * 256];

    int tid = threadIdx.x;
    int wave = tid >> 6, lane = tid & 63;
    int lr = lane & 15, kg = lane >> 4;
    int m0 = blockIdx.x * 128 + wave * 16;

    const ushort_t* Ab0 = A + (long long)(m0 + lr) * 256 + kg * 8;
    const ushort_t* Ab1 = Ab0 + 64 * 256;
    bf16x8 areg0[8], areg1[8];
    #pragma unroll
    for (int kb = 0; kb < 8; kb++) {
        areg0[kb] = *(const bf16x8*)(Ab0 + kb * 32);
        areg1[kb] = *(const bf16x8*)(Ab1 + kb * 32);
    }

    float rs0[4] = {0.f, 0.f, 0.f, 0.f};
    float rs1[4] = {0.f, 0.f, 0.f, 0.f};

    for (int ph = 0; ph < 4; ph++) {
        int n0 = ph * 64;
        #pragma unroll
        for (int step = 0; step < 8; step++) {
            int g = step * 256 + tid;
            int row = g >> 5, slot = g & 31;
            uint4 v = *(const uint4*)(W + (long long)(n0 + row) * 256 + slot * 8);
            int dst = row * 512 + ((slot * 16) ^ ((row & 31) << 4));
            *(uint4*)((char*)Bs + dst) = v;
        }
        __syncthreads();

        {
            f32x4 acc[4];
            #pragma unroll
            for (int t = 0; t < 4; t++) acc[t] = (f32x4){0.f, 0.f, 0.f, 0.f};
            #pragma unroll
            for (int kb = 0; kb < 8; kb++) {
                #pragma unroll
                for (int t = 0; t < 4; t++) {
                    int rowl = t * 16 + lr;
                    int colb = (kg * 16 + kb * 64) ^ ((rowl & 31) << 4);
                    bf16x8 b = *(const bf16x8*)((char*)Bs + rowl * 512 + colb);
                    acc[t] = __builtin_amdgcn_mfma_f32_16x16x32_bf16(areg0[kb], b, acc[t], 0, 0, 0);
                }
            }
            #pragma unroll
            for (int t = 0; t < 4; t++) {
                int col = n0 + t * 16 + lr;
                float bv = bias[col], wv = w2[col];
                #pragma unroll
                for (int r = 0; r < 4; r++)
                    rs0[r] += ftanh(acc[t][r] + bv) * wv;
            }
        }
        {
            f32x4 acc[4];
            #pragma unroll
            for (int t = 0; t < 4; t++) acc[t] = (f32x4){0.f, 0.f, 0.f, 0.f};
            #pragma unroll
            for (int kb = 0; kb < 8; kb++) {
                #pragma unroll
                for (int t = 0; t < 4; t++) {
                    int rowl = t * 16 + lr;
                    int colb = (kg * 16 + kb * 64) ^ ((rowl & 31) << 4);
                    bf16x8 b = *(const bf16x8*)((char*)Bs + rowl * 512 + colb);
                    acc[t] = __builtin_amdgcn_mfma_f32_16x16x32_bf16(areg1[kb], b, acc[t], 0, 0, 0);
                }
            }
            #pragma unroll
            for (int t = 0; t < 4; t++) {
                int col = n0 + t * 16 + lr;
                float bv = bias[col], wv = w2[col];
                #pragma unroll
                for (int r = 0; r < 4; r++)
                    rs1[r] += ftanh(acc[t][r] + bv) * wv;
            }
        }
        __syncthreads();
    }

    #pragma unroll
    for (int r = 0; r < 4; r++) {
        rs0[r] += __shfl_xor(rs0[r], 1, 64);
        rs0[r] += __shfl_xor(rs0[r], 2, 64);
        rs0[r] += __shfl_xor(rs0[r], 4, 64);
        rs0[r] += __shfl_xor(rs0[r], 8, 64);
        rs1[r] += __shfl_xor(rs1[r], 1, 64);
        rs1[r] += __shfl_xor(rs1[r], 2, 64);
        rs1[r] += __shfl_xor(rs1[r], 4, 64);
        rs1[r] += __shfl_xor(rs1[r], 8, 64);
    }
    if (lr == 0) {
        int row0 = m0 + kg * 4;
        #pragma unroll
        for (int r = 0; r < 4; r++) {
            Cz[row0 + r] = rs0[r];
            Cz[row0 + 64 + r] = rs1[r];
        }
    }
}

// pack biases and w2 vectors for z=8 fused reduce
__global__ __launch_bounds__(256) void pack8_k(
    const float* __restrict__ b1, const float* __restrict__ b2,
    const float* __restrict__ w1, int w1Off,
    const float* __restrict__ w2v, int w2Off,
    float* __restrict__ bias8, float* __restrict__ w28)
{
    int j = blockIdx.x * 256 + threadIdx.x;
    int slot = j >> 8, c = j & 255;
    bias8[j] = slot < 4 ? b1[slot * 256 + c] : b2[(slot - 4) * 256 + c];
    w28[j]   = slot < 4 ? w1[slot * 512 + w1Off + c] : w2v[(slot - 4) * 512 + w2Off + c];
}

// ---------------------------------------------------------------------------
// fused BIDAT A-chain, MT=4 m-tiles, avU in registers
// ---------------------------------------------------------------------------
__global__ __launch_bounds__(256) void bidat_fused_k(
    const ushort_t* __restrict__ avU_all,
    const ushort_t* __restrict__ pv_bf,
    const float* __restrict__ rbuf_all,
    const float* __restrict__ qbuf_all,
    const float* __restrict__ atoms_mask,
    const float* __restrict__ amino_mask,
    float* __restrict__ scoreCp,
    float* __restrict__ csump)
{
    int z = blockIdx.z;
    int i = z >> 5, b = z & 31;
    int gx = blockIdx.x;
    int gy = blockIdx.y;
    int wave = threadIdx.x >> 6;
    int lane = threadIdx.x & 63;
    int lr = lane & 15, kg = lane >> 4;

    int n0 = gx * 64 + wave * 16;
    const ushort_t* Ab = avU_all + ((long long)i * 4096 + (long long)b * 128 + n0 + lr) * 256 + kg * 8;
    bf16x8 areg[8];
    #pragma unroll
    for (int kb = 0; kb < 8; kb++) areg[kb] = *(const bf16x8*)(Ab + kb * 32);

    const float* rI = rbuf_all + (long long)i * 32768 + (long long)b * 1024;
    const float* qI = qbuf_all + (long long)i * 4096 + (long long)b * 128;
    const float* mR = atoms_mask + (long long)b * 128;
    const float* mC = amino_mask + (long long)b * 1024;

    float mRn[4], qn[4];
    #pragma unroll
    for (int r = 0; r < 4; r++) {
        int n = n0 + kg * 4 + r;
        mRn[r] = mR[n];
        qn[r]  = qI[n];
    }

    float sc[4] = {0.f, 0.f, 0.f, 0.f};
    __shared__ float cl[4][64];

    for (int mt = 0; mt < 4; mt++) {
        int m0 = (gy * 4 + mt) * 64;
        const ushort_t* Bb = pv_bf + ((long long)b * 1024 + m0 + lr) * 256 + kg * 8;

        f32x4 acc[4];
        #pragma unroll
        for (int t = 0; t < 4; t++) acc[t] = (f32x4){0.f, 0.f, 0.f, 0.f};
        #pragma unroll
        for (int kb = 0; kb < 8; kb++) {
            #pragma unroll
            for (int t = 0; t < 4; t++) {
                bf16x8 bfr = *(const bf16x8*)(Bb + (long long)t * 16 * 256 + kb * 32);
                acc[t] = __builtin_amdgcn_mfma_f32_16x16x32_bf16(areg[kb], bfr, acc[t], 0, 0, 0);
            }
        }

        float cs[4] = {0.f, 0.f, 0.f, 0.f};
        #pragma unroll
        for (int t = 0; t < 4; t++) {
            int m = m0 + t * 16 + lr;
            float mc = mC[m];
            float rv = rI[m];
            #pragma unroll
            for (int r = 0; r < 4; r++) {
                float a = ftanh(acc[t][r]) * mRn[r] * mc;
                sc[r] += a * rv;
                cs[t] += a * qn[r];
            }
        }
        #pragma unroll
        for (int t = 0; t < 4; t++) {
            cs[t] += __shfl_xor(cs[t], 16, 64);
            cs[t] += __shfl_xor(cs[t], 32, 64);
        }
        __syncthreads();
        if (kg == 0) {
            #pragma unroll
            for (int t = 0; t < 4; t++) cl[wave][t * 16 + lr] = cs[t];
        }
        __syncthreads();
        if (threadIdx.x < 64) {
            float s = cl[0][threadIdx.x] + cl[1][threadIdx.x]
                    + cl[2][threadIdx.x] + cl[3][threadIdx.x];
            csump[((long long)z * 2 + gx) * 1024 + m0 + threadIdx.x] = s;
        }
    }

    #pragma unroll
    for (int r = 0; r < 4; r++) {
        sc[r] += __shfl_xor(sc[r], 1, 64);
        sc[r] += __shfl_xor(sc[r], 2, 64);
        sc[r] += __shfl_xor(sc[r], 4, 64);
        sc[r] += __shfl_xor(sc[r], 8, 64);
    }
    if (lr == 0) {
        #pragma unroll
        for (int r = 0; r < 4; r++) {
            int n = gx * 64 + wave * 16 + kg * 4 + r;
            scoreCp[((long long)z * 4 + gy) * 128 + n] = sc[r];
        }
    }
}

// finishC + masked softmax fused
__global__ __launch_bounds__(128) void finishC_sm_k(
    const float* __restrict__ scoreCp, const float* __restrict__ hbdot_all,
    const float* __restrict__ battc_b, const float* __restrict__ mask,
    float* __restrict__ scoreC_all)
{
    int z = blockIdx.x;
    int i = z >> 5, b = z & 31;
    int n = threadIdx.x;
    __shared__ float red[128];
    float s = 0.f;
    #pragma unroll
    for (int gy = 0; gy < 4; gy++)
        s += scoreCp[((long long)z * 4 + gy) * 128 + n];
    s += hbdot_all[(long long)i * 4096 + b * 128 + n] + battc_b[i];
    red[n] = s; __syncthreads();
    for (int off = 64; off > 0; off >>= 1) {
        if (n < off) red[n] = fmaxf(red[n], red[n + off]);
        __syncthreads();
    }
    float mx = red[0];
    __syncthreads();
    float e = __expf(s - mx) * mask[(long long)b * 128 + n];
    red[n] = e; __syncthreads();
    for (int off = 64; off > 0; off >>= 1) {
        if (n < off) red[n] += red[n + off];
        __syncthreads();
    }
    float inv = 1.0f / (red[0] + 1e-6f);
    scoreC_all[(long long)z * 128 + n] = e * inv;
}

// finishP + masked softmax fused
__global__ __launch_bounds__(256) void finishP_sm_k(
    const float* __restrict__ csump, const float* __restrict__ hpbdot_all,
    const float* __restrict__ battp_b, const float* __restrict__ mask,
    float* __restrict__ scoreP_all)
{
    int z = blockIdx.x;
    int i = z >> 5, b = z & 31;
    int t = threadIdx.x;
    __shared__ float red[256];
    float vals[4];
    float mx = -1e30f;
    #pragma unroll
    for (int j = 0; j < 4; j++) {
        int m = j * 256 + t;
        float s = csump[((long long)z * 2 + 0) * 1024 + m]
                + csump[((long long)z * 2 + 1) * 1024 + m]
                + hpbdot_all[(long long)i * 32768 + (long long)b * 1024 + m]
                + battp_b[i];
        vals[j] = s;
        mx = fmaxf(mx, s);
    }
    red[t] = mx; __syncthreads();
    for (int off = 128; off > 0; off >>= 1) {
        if (t < off) red[t] = fmaxf(red[t], red[t + off]);
        __syncthreads();
    }
    mx = red[0];
    __syncthreads();
    float sum = 0.f;
    #pragma unroll
    for (int j = 0; j < 4; j++) {
        float e = __expf(vals[j] - mx) * mask[(long long)b * 1024 + j * 256 + t];
        vals[j] = e; sum += e;
    }
    red[t] = sum; __syncthreads();
    for (int off = 128; off > 0; off >>= 1) {
        if (t < off) red[t] += red[t + off];
        __syncthreads();
    }
    float inv = 1.0f / (red[0] + 1e-6f);
    #pragma unroll
    for (int j = 0; j < 4; j++)
        scoreP_all[(long long)z * 1024 + j * 256 + t] = vals[j] * inv;
}

// fp32 [rows][Ksrc] -> bf16 [rows][Kdst] zero-padded (atoms_emb only)
__global__ __launch_bounds__(256) void cvtpad_bf16_k(
    const float* __restrict__ in, ushort_t* __restrict__ out,
    int rows, int Ksrc, int Kdst)
{
    long long idx = (long long)blockIdx.x * 256 + threadIdx.x;
    long long total = (long long)rows * Kdst;
    if (idx >= total) return;
    int r = (int)(idx / Kdst), k = (int)(idx % Kdst);
    out[idx] = (k < Ksrc) ? f2bf(in[(long long)r * Ksrc + k]) : (ushort_t)0;
}

// ---------------------------------------------------------------------------
// all weight transpose-converts in one table-driven launch
// ---------------------------------------------------------------------------
struct WtEnt {
    const float* W; ushort_t* Wt;
    int K, Nsrc, Npad, Kp, zcnt, blkStart;
};
struct WtTab { WtEnt e[11]; };

__global__ __launch_bounds__(256) void wtcvtAll_k(WtTab tab)
{
    int blk = blockIdx.x;
    int ei = 0;
    #pragma unroll
    for (int i = 1; i < 11; i++) if (blk >= tab.e[i].blkStart) ei = i;
    WtEnt E = tab.e[ei];
    long long perZ = (long long)E.Npad * E.Kp;
    long long lidx = (long long)(blk - E.blkStart) * 256 + threadIdx.x;
    if (lidx >= perZ * E.zcnt) return;
    int z = (int)(lidx / perZ);
    long long idx = lidx % perZ;
    int n = (int)(idx / E.Kp), k = (int)(idx % E.Kp);
    const float* Wz = E.W + (long long)z * E.K * E.Nsrc;
    ushort_t* Oz = E.Wt + (long long)z * perZ;
    float v = (k < E.K && n < E.Nsrc) ? Wz[(long long)k * E.Nsrc + n] : 0.f;
    Oz[idx] = f2bf(v);
}

// per-row GAT source/dest attention logits
__global__ __launch_bounds__(128) void gat_e_k(
    const float* __restrict__ Wh, int ldWh, int GD,
    const float* __restrict__ a, int aStride,
    float* __restrict__ esrc, float* __restrict__ edst, int rows)
{
    int row = blockIdx.x;
    int k = blockIdx.y;
    int g = threadIdx.x;
    float ws = 0.f, wd = 0.f;
    if (g < GD) {
        float wv = Wh[(long long)row * ldWh + k * GD + g];
        ws = wv * a[k * aStride + g];
        wd = wv * a[k * aStride + GD + g];
    }
    __shared__ float sb[2][128];
    sb[0][threadIdx.x] = ws; sb[1][threadIdx.x] = wd;
    __syncthreads();
    for (int off = 64; off > 0; off >>= 1) {
        if (threadIdx.x < off) {
            sb[0][threadIdx.x] += sb[0][threadIdx.x + off];
            sb[1][threadIdx.x] += sb[1][threadIdx.x + off];
        }
        __syncthreads();
    }
    if (threadIdx.x == 0) {
        esrc[(long long)k * rows + row] = sb[0][0];
        edst[(long long)k * rows + row] = sb[1][0];
    }
}

// ---------------------------------------------------------------------------
// GAT attention, 256-thread blocks, bf16 output
// ---------------------------------------------------------------------------
template<int GD>
__global__ __launch_bounds__(256) void gat_attn2_k(
    const float* __restrict__ Wh, int ldWh,
    const int* __restrict__ adj,
    const float* __restrict__ esrc, const float* __restrict__ edst,
    ushort_t* __restrict__ outp, int ldOut)
{
    int row = blockIdx.x;          // b*N + n
    int k = blockIdx.y;
    int rows = gridDim.x;
    int b = row >> 7, n = row & 127;
    int tid = threadIdx.x;

    __shared__ float att[128];
    __shared__ float red[128];
    __shared__ float sred[256];

    if (tid < 128) {
        float e = esrc[(long long)k * rows + row] + edst[(long long)k * rows + b * 128 + tid];
        e = e > 0.f ? e : ALPHA_LR * e;
        if (adj[(long long)b * 16384 + n * 128 + tid] <= 0) e = -9.0e15f;
        att[tid] = e;
        red[tid] = e;
    }
    __syncthreads();
    for (int off = 64; off > 0; off >>= 1) {
        if (tid < off) red[tid] = fmaxf(red[tid], red[tid + off]);
        __syncthreads();
    }
    float mx = red[0];
    __syncthreads();
    if (tid < 128) {
        float ex = __expf(att[tid] - mx);
        att[tid] = ex;
        red[tid] = ex;
    }
    __syncthreads();
    for (int off = 64; off > 0; off >>= 1) {
        if (tid < off) red[tid] += red[tid + off];
        __syncthreads();
    }
    float inv = 1.0f / red[0];
    __syncthreads();

    constexpr int SPLIT = 256 / GD;
    constexpr int CH = 128 / SPLIT;
    int g = tid % GD;
    int part = tid / GD;
    const float* Whb = Wh + (long long)(b * 128) * ldWh + k * GD + g;
    float s = 0.f;
    int mm0 = part * CH;
    for (int mm = mm0; mm < mm0 + CH; mm++)
        s += att[mm] * Whb[(long long)mm * ldWh];
    sred[part * GD + g] = s;
    __syncthreads();
    if (part == 0) {
        float tot = s;
        #pragma unroll
        for (int p = 1; p < SPLIT; p++) tot += sred[p * GD + g];
        tot *= inv;
        tot = tot > 0.f ? tot : expm1f(tot);   // ELU
        outp[(long long)row * ldOut + k * GD + g] = f2bf(tot);
    }
}

// ---------------------------------------------------------------------------
// fused 3x 11x11 conv chain, fully LDS-resident.
// one block = 64 m-rows x 1 batch: load input tile + 15-row halo into LDS with
// zero-padded d-columns (no inner-loop bounds checks), then conv1 (84 rows)
// -> conv2 (74) -> conv3 (64, written as padded bf16 [.][64] directly).
// grid (16, 32), 256 thr, ~51 KB LDS (3 blocks/CU).
// ---------------------------------------------------------------------------
__global__ __launch_bounds__(256) void conv3_k(
    const float* __restrict__ x,        // [32][1024][40] (pv0 out)
    const float* __restrict__ Wc,       // [3][121]
    const float* __restrict__ bc,       // [3]
    ushort_t* __restrict__ y)           // [32768][64] bf16, d>=40 zero
{
    __shared__ float wsh[3][121];
    __shared__ float A[94][50];
    __shared__ float Bv[84][50];
    __shared__ float Cv[74][50];

    int tid = threadIdx.x;
    int b = blockIdx.y;
    int m0 = blockIdx.x * 64;

    for (int i = tid; i < 363; i += 256) wsh[i / 121][i % 121] = Wc[i];
    // load input tile rows [m0-15, m0+79), cols padded by 5 each side
    const float* xb = x + (long long)b * Mq * PDq;
    for (int idx = tid; idx < 94 * 50; idx += 256) {
        int row = idx / 50, col = idx % 50;
        int gm = m0 - 15 + row, d = col - 5;
        float v = 0.f;
        if (d >= 0 && d < PDq && gm >= 0 && gm < Mq)
            v = xb[(long long)gm * PDq + d];
        A[row][col] = v;
    }
    __syncthreads();

    // conv1: Bv rows 0..83 (gm = m0-10+row)
    {
        float b0 = bc[0];
        for (int idx = tid; idx < 84 * 50; idx += 256) {
            int row = idx / 50, col = idx % 50;
            float s = 0.f;
            if (col >= 5 && col < 45) {
                int d = col - 5;
                #pragma unroll
                for (int i = 0; i < 11; i++)
                    #pragma unroll
                    for (int j = 0; j < 11; j++)
                        s += A[row + i][d + j] * wsh[0][i * 11 + j];
                s += b0;
                s = s > 0.f ? s : ALPHA_LR * s;
            }
            Bv[row][col] = s;
        }
    }
    __syncthreads();

    // conv2: Cv rows 0..73 (gm = m0-5+row)
    {
        float b1 = bc[1];
        for (int idx = tid; idx < 74 * 50; idx += 256) {
            int row = idx / 50, col = idx % 50;
            float s = 0.f;
            if (col >= 5 && col < 45) {
                int d = col - 5;
                #pragma unroll
                for (int i = 0; i < 11; i++)
                    #pragma unroll
                    for (int j = 0; j < 11; j++)
                        s += Bv[row + i][d + j] * wsh[1][i * 11 + j];
                s += b1;
                s = s > 0.f ? s : ALPHA_LR * s;
            }
            Cv[row][col] = s;
        }
    }
    __syncthreads();

    // conv3: output rows 0..63 (gm = m0+row), write padded bf16 [.][64]
    {
        float b2 = bc[2];
        for (int idx = tid; idx < 64 * 64; idx += 256) {
            int row = idx / 64, d = idx % 64;
            long long o = ((long long)b * Mq + m0 + row) * 64 + d;
            if (d >= PDq) { y[o] = 0; continue; }
            float s = 0.f;
            #pragma unroll
            for (int i = 0; i < 11; i++)
                #pragma unroll
                for (int j = 0; j < 11; j++)
                    s += Cv[row + i][d + j] * wsh[2][i * 11 + j];
            s += b2;
            s = s > 0.f ? s : ALPHA_LR * s;
            y[o] = f2bf(s);
        }
    }
}

// weighted sum stage 1 for ALL 4 i per feat read
__global__ __launch_bounds__(256) void wsum1B4_k(
    const ushort_t* __restrict__ feat, const float* __restrict__ att_all,
    float* __restrict__ partial, int L)
{
    int b = blockIdx.x, c = blockIdx.y, l = threadIdx.x;
    int chunk = L / 16;
    const ushort_t* fb = feat + (long long)b * L * LDq;
    const float* a0 = att_all + ((long long)0 * Bq + b) * L;
    const float* a1 = att_all + ((long long)1 * Bq + b) * L;
    const float* a2 = att_all + ((long long)2 * Bq + b) * L;
    const float* a3 = att_all + ((long long)3 * Bq + b) * L;
    float s0 = 0.f, s1 = 0.f, s2 = 0.f, s3 = 0.f;
    int r0 = c * chunk, r1 = r0 + chunk;
    for (int r = r0; r < r1; r++) {
        float f = bf2f(fb[(long long)r * LDq + l]);
        s0 += f * a0[r]; s1 += f * a1[r];
        s2 += f * a2[r]; s3 += f * a3[r];
    }
    partial[(((long long)0 * Bq + b) * 16 + c) * LDq + l] = s0;
    partial[(((long long)1 * Bq + b) * 16 + c) * LDq + l] = s1;
    partial[(((long long)2 * Bq + b) * 16 + c) * LDq + l] = s2;
    partial[(((long long)3 * Bq + b) * 16 + c) * LDq + l] = s3;
}

// weighted sum stage 2, batched
__global__ __launch_bounds__(256) void wsum2B_k(
    const float* __restrict__ partial, float* __restrict__ out)
{
    int b = blockIdx.x, i = blockIdx.y, l = threadIdx.x;
    float s = 0.f;
    #pragma unroll
    for (int c = 0; c < 16; c++)
        s += partial[(((long long)i * Bq + b) * 16 + c) * LDq + l];
    out[(long long)b * 4 * LDq + i * LDq + l] = s;
}

// ---------------------------------------------------------------------------
// Skinny dense layer for the head
// ---------------------------------------------------------------------------
template<int ACT>
__global__ __launch_bounds__(256) void headlin_k(
    const float* __restrict__ vin, int ldv, int VD,
    const float* __restrict__ W, int ldw,
    const float* __restrict__ bias,
    float* __restrict__ vout, int ldo, int OD, int colBase)
{
    int b = blockIdx.x;
    int c = threadIdx.x & 63;
    int s = threadIdx.x >> 6;
    int col = blockIdx.y * 64 + c;

    __shared__ float vs[1024];
    for (int i = threadIdx.x; i < VD; i += 256) vs[i] = vin[(long long)b * ldv + i];
    __syncthreads();

    float sum = 0.f;
    if (col < OD) {
        int k0 = (VD * s) >> 2, k1 = (VD * (s + 1)) >> 2;
        #pragma unroll 4
        for (int k = k0; k < k1; k++)
            sum += vs[k] * W[(long long)k * ldw + col];
    }
    __shared__ float red[4][64];
    red[s][c] = sum;
    __syncthreads();
    if (s == 0 && col < OD) {
        float t = red[0][c] + red[1][c] + red[2][c] + red[3][c] + bias[col];
        if (ACT == 1) t = t > 0.f ? t : ALPHA_LR * t;
        vout[(long long)b * ldo + colBase + col] = t;
    }
}

// v[b,256:512]=fps, v[b,768]=invT, v[b,769]=T
__global__ __launch_bounds__(256) void vfill_k(
    const float* __restrict__ fps, const float* __restrict__ invT,
    const float* __restrict__ T, float* __restrict__ v)
{
    int b = blockIdx.x, t = threadIdx.x;
    v[(long long)b * 770 + 256 + t] = fps[(long long)b * 256 + t];
    if (t == 0) {
        v[(long long)b * 770 + 768] = invT[b];
        v[(long long)b * 770 + 769] = T[b];
    }
}

// out[b] = v[b,:770]·W + b
__global__ __launch_bounds__(256) void final_k(
    const float* __restrict__ v, const float* __restrict__ W,
    const float* __restrict__ bptr, float* __restrict__ out)
{
    int b = blockIdx.x, t = threadIdx.x;
    float s = 0.f;
    for (int i = t; i < 770; i += 256) s += v[(long long)b * 770 + i] * W[i];
    __shared__ float red[256];
    red[t] = s; __syncthreads();
    for (int off = 128; off > 0; off >>= 1) {
        if (t < off) red[t] += red[t + off];
        __syncthreads();
    }
    if (t == 0) out[b] = red[0] + bptr[0];
}

extern "C" void kernel_launch(void* const* d_in, const int* in_sizes, int n_in,
                              void* d_out, int out_size, void* d_ws, size_t ws_size,
                              hipStream_t stream)
{
    const float* atoms_emb = (const float*)d_in[0];
    const int*   adjacency = (const int*)d_in[1];
    const float* atoms_mask= (const float*)d_in[2];
    const float* amino_emb = (const float*)d_in[3];
    const float* amino_mask= (const float*)d_in[4];
    const float* fps       = (const float*)d_in[5];
    const float* inv_Temp  = (const float*)d_in[6];
    const float* Temp      = (const float*)d_in[7];
    const float* bert_W    = (const float*)d_in[8];
    const float* bert_b    = (const float*)d_in[9];
    const float* gat_W     = (const float*)d_in[10];
    const float* gat_a     = (const float*)d_in[11];
    const float* gatout_W  = (const float*)d_in[12];
    const float* gatout_a  = (const float*)d_in[13];
    const float* Wcomp_W   = (const float*)d_in[14];
    const float* Wcomp_b   = (const float*)d_in[15];
    const float* prot_W    = (const float*)d_in[16];
    const float* prot_b    = (const float*)d_in[17];
    const float* conv_W    = (const float*)d_in[18];
    const float* conv_b    = (const float*)d_in[19];
    const float* Wprot_W   = (const float*)d_in[20];
    const float* Wprot_b   = (const float*)d_in[21];
    const float* U         = (const float*)d_in[22];
    const float* tc2p_W    = (const float*)d_in[23];
    const float* tc2p_b    = (const float*)d_in[24];
    const float* tp2c_W    = (const float*)d_in[25];
    const float* tp2c_b    = (const float*)d_in[26];
    const float* bhc_W     = (const float*)d_in[27];
    const float* bhc_b     = (const float*)d_in[28];
    const float* bhp_W     = (const float*)d_in[29];
    const float* bhp_b     = (const float*)d_in[30];
    const float* battc_W   = (const float*)d_in[31];
    const float* battc_b   = (const float*)d_in[32];
    const float* battp_W   = (const float*)d_in[33];
    const float* battp_b   = (const float*)d_in[34];
    const float* combc_W   = (const float*)d_in[35];
    const float* combc_b   = (const float*)d_in[36];
    const float* combp_W   = (const float*)d_in[37];
    const float* combp_b   = (const float*)d_in[38];
    const float* Wout_W    = (const float*)d_in[39];
    const float* Wout_b    = (const float*)d_in[40];
    const float* out_W     = (const float*)d_in[41];
    const float* out_b     = (const float*)d_in[42];
    float* out = (float*)d_out;

    // ---- workspace layout (floats) ----
    float* w = (float*)d_ws;
    float* av    = w; w += (long long)Bq*Nq*LDq;
    float* pv    = w; w += (long long)Bq*Mq*LDq;
    float* sx    = w; w += (long long)Bq*Mq*LDq;   // early fp32 scratch -> precomp pool
    float* pool  = w; w += (long long)Bq*Nq*Mq;    // early bf16 staging -> partials
    float* bufU  = w; w += (long long)Bq*Nq*LDq;
    float* bufTC = w; w += (long long)Bq*Nq*LDq;   // wsum partials
    float* esrc  = w; w += (long long)NHq*Bq*Nq;
    float* edst  = w; w += (long long)NHq*Bq*Nq;
    float* scoreC= w; w += (long long)Bq*Nq;
    float* scoreP= w; w += (long long)Bq*Mq;
    float* rbuf  = w; w += (long long)Bq*Mq;       // -> pack8 outputs
    float* qbuf  = w; w += (long long)Bq*Nq;
    float* csum  = w; w += (long long)Bq*Mq;
    float* cf    = w; w += (long long)Bq*4*LDq;
    float* pf    = w; w += (long long)Bq*4*LDq;
    float* v1    = w; w += (long long)Bq*770;
    float* v2    = w; w += (long long)Bq*770;
    // bf16 buffers
    ushort_t* pv_bf  = (ushort_t*)w; w += (long long)Bq*Mq*LDq/2;
    ushort_t* av_bf  = (ushort_t*)w; w += (long long)Bq*Nq*LDq/2;
    ushort_t* avU_bf = (ushort_t*)w; w += (long long)Bq*Nq*LDq/2;
    ushort_t* Ut_bf     = (ushort_t*)w; w += (long long)4*LDq*LDq/2;
    ushort_t* protWt_bf = (ushort_t*)w; w += (long long)48*1024/2;
    ushort_t* bertWt_bf = (ushort_t*)w; w += (long long)128*320/2;
    ushort_t* gatWt_bf  = (ushort_t*)w; w += (long long)4*64*128/2;
    ushort_t* gatoutWt_bf=(ushort_t*)w; w += (long long)128*256/2;
    ushort_t* WcompT_bf = (ushort_t*)w; w += (long long)256*128/2;
    ushort_t* WprotT_bf = (ushort_t*)w; w += (long long)256*64/2;
    ushort_t* wP_bf     = (ushort_t*)w; w += (long long)8*256*256/2;
    ushort_t* wA_bf     = (ushort_t*)w; w += (long long)8*256*256/2;

    int rowsA = Bq * Nq;     // 4096
    int rowsP = Bq * Mq;     // 32768

    // early fp32 aliases inside sx (dead before BIDAT precompute)
    float* h     = sx;
    float* WhAll = h + (long long)rowsA*CDq;
    float* multi = WhAll + (long long)rowsA*NHq*GDq;
    float* Wh2   = multi + (long long)rowsA*NHq*GDq;
    float* avp   = Wh2 + (long long)rowsA*CDq;
    float* c0    = avp + (long long)rowsA*CDq;
    float* c1    = c0 + (long long)rowsP*PDq;

    // early bf16 aliases inside pool (dead before partials phase)
    ushort_t* atoms_bf = (ushort_t*)pool;
    ushort_t* h_bf     = atoms_bf + (long long)rowsA*320;
    ushort_t* multi_bf = h_bf + (long long)rowsA*128;
    ushort_t* avp_bf   = multi_bf + (long long)rowsA*256;
    ushort_t* c1_bf    = avp_bf + (long long)rowsA*128;

    // BIDAT-precompute pool in sx (z=8 reduce outputs land contiguously)
    float*    rbuf_all   = sx;
    float*    hpbdot_all = rbuf_all   + (long long)4*rowsP;
    float*    qbuf_all   = hpbdot_all + (long long)4*rowsP;
    float*    hbdot_all  = qbuf_all   + (long long)4*rowsA;
    float*    bufU_all   = hbdot_all  + (long long)4*rowsA;
    ushort_t* avU_all_bf = (ushort_t*)(bufU_all + (long long)4*rowsA*LDq);

    // partials pool (after bidat)
    float* scoreCp    = pool;                        // 128*4*128
    float* csump      = scoreCp + 65536;             // 128*2*1024
    float* scoreC_all = csump + 262144;              // 16384
    float* scoreP_all = scoreC_all + 16384;          // 131072

    float* wpart = bufTC;

    // pack8 outputs
    float* bias8P = rbuf;
    float* w28P   = rbuf + 2048;
    float* bias8A = rbuf + 4096;
    float* w28A   = rbuf + 6144;

    // ---- single table-driven weight convert launch ----
    WtTab tab;
    int blk = 0;
    auto setent = [&](int i, const float* W, ushort_t* Wt,
                      int K, int Nsrc, int Npad, int Kp, int zc) {
        tab.e[i].W = W; tab.e[i].Wt = Wt;
        tab.e[i].K = K; tab.e[i].Nsrc = Nsrc; tab.e[i].Npad = Npad;
        tab.e[i].Kp = Kp; tab.e[i].zcnt = zc; tab.e[i].blkStart = blk;
        blk += (int)(((long long)zc * Npad * Kp + 255) / 256);
    };
    setent(0,  U,        Ut_bf,       256, 256, 256, 256, 4);
    setent(1,  prot_W,   protWt_bf,   1024, 40, 48, 1024, 1);
    setent(2,  bert_W,   bertWt_bf,   300, 128, 128, 320, 1);
    setent(3,  gat_W,    gatWt_bf,    128, 64,  64,  128, 4);
    setent(4,  gatout_W, gatoutWt_bf, 256, 128, 128, 256, 1);
    setent(5,  Wcomp_W,  WcompT_bf,   128, 256, 256, 128, 1);
    setent(6,  Wprot_W,  WprotT_bf,   40,  256, 256, 64,  1);
    setent(7,  tp2c_W,   wP_bf,              256, 256, 256, 256, 4);
    setent(8,  bhp_W,    wP_bf + 4*65536,    256, 256, 256, 256, 4);
    setent(9,  tc2p_W,   wA_bf,              256, 256, 256, 256, 4);
    setent(10, bhc_W,    wA_bf + 4*65536,    256, 256, 256, 256, 4);
    wtcvtAll_k<<<blk, 256, 0, stream>>>(tab);
    pack8_k<<<8, 256, 0, stream>>>(tp2c_b, bhp_b, battc_W, 256, battp_W, 0, bias8P, w28P);
    pack8_k<<<8, 256, 0, stream>>>(tc2p_b, bhc_b, battp_W, 0, battc_W, 0, bias8A, w28A);
    // NOTE: battp_W offset for A-side w2 is 0 (hbdot uses battc[256:]? see r13 mapping)
    // r13-verified mapping restored below (identical to r18):
    pack8_k<<<8, 256, 0, stream>>>(tc2p_b, bhc_b, battp_W, 256, battc_W, 0, bias8A, w28A);

    // 1. h = atoms_emb @ bert_W + bert_b  (MFMA, K padded, bf16 out direct)
    cvtpad_bf16_k<<<(int)(((long long)rowsA*320 + 255)/256), 256, 0, stream>>>(
        atoms_emb, atoms_bf, rowsA, 300, 320);
    mfma_nt_k<0, 0, 1, 2, 0, 1><<<dim3(rowsA/64, 4, 1), 256, 0, stream>>>(
        rowsA, CDq, 320, CDq, (const void*)atoms_bf, 320, 0,
        bertWt_bf, 320, 0, bert_b, 0, (void*)h_bf, CDq, 0, nullptr, 0, nullptr);

    // 2. Wh_all = h @ gat_W[k]  (MFMA, z=4, fp32 out for gat_e)
    mfma_nt_k<0, 0, 0, 4, 0, 0><<<dim3(rowsA/64, 1, 4), 256, 0, stream>>>(
        rowsA, GDq, CDq, GDq, (const void*)h_bf, CDq, 0,
        gatWt_bf, CDq, (long long)GDq*CDq,
        nullptr, 0, (void*)WhAll, NHq*GDq, GDq, nullptr, 0, nullptr);

    // 3-4. GAT heads -> multi_bf (ELU, bf16 out direct)
    gat_e_k<<<dim3(rowsA, NHq), 128, 0, stream>>>(WhAll, NHq*GDq, GDq, gat_a, 2*GDq,
                                                  esrc, edst, rowsA);
    gat_attn2_k<64><<<dim3(rowsA, NHq), 256, 0, stream>>>(WhAll, NHq*GDq, adjacency,
                                                          esrc, edst, multi_bf, NHq*GDq);

    // 5-7. GAT out layer -> avp_bf (ELU)
    mfma_nt_k<0, 0, 0, 2, 0, 0><<<dim3(rowsA/64, 4, 1), 256, 0, stream>>>(
        rowsA, CDq, 256, CDq, (const void*)multi_bf, 256, 0,
        gatoutWt_bf, 256, 0, nullptr, 0, (void*)Wh2, CDq, 0, nullptr, 0, nullptr);
    gat_e_k<<<dim3(rowsA, 1), 128, 0, stream>>>(Wh2, CDq, CDq, gatout_a, 2*CDq,
                                                esrc, edst, rowsA);
    gat_attn2_k<128><<<dim3(rowsA, 1), 256, 0, stream>>>(Wh2, CDq, adjacency,
                                                         esrc, edst, avp_bf, CDq);

    // 8. av = leaky(avp @ Wcomp_W + b)  (MFMA, bf16 out direct)
    mfma_nt_k<1, 0, 1, 4, 0, 1><<<dim3(rowsA/64, 4, 1), 256, 0, stream>>>(
        rowsA, LDq, CDq, LDq, (const void*)avp_bf, CDq, 0,
        WcompT_bf, CDq, 0, Wcomp_b, 0, (void*)av_bf, LDq, 0, nullptr, 0, nullptr);

    // 9. pv0 = amino_emb @ prot_W + b  (LDS-staged coalesced kernel)
    pv0_k<<<rowsP/64, 256, 0, stream>>>(amino_emb, protWt_bf, prot_b, c0);

    // 10. fused 3x conv chain, LDS-resident, bf16 padded out
    conv3_k<<<dim3(Mq/64, Bq), 256, 0, stream>>>(c0, conv_W, conv_b, c1_bf);

    // 11. pv = leaky(x @ Wprot_W + b)  (MFMA, bf16 out direct)
    mfma_nt_k<1, 0, 1, 4, 0, 1><<<dim3(rowsP/64, 4, 1), 256, 0, stream>>>(
        rowsP, LDq, 64, LDq, (const void*)c1_bf, 64, 0,
        WprotT_bf, 64, 0, Wprot_b, 0, (void*)pv_bf, LDq, 0, nullptr, 0, nullptr);

    // ---- BIDAT precompute: fused z=8 reduces (MT=2 row-tiles) ----
    mfma_reduceF_k<<<dim3(rowsP/128, 1, 8), 256, 0, stream>>>(
        rowsP, pv_bf, wP_bf, bias8P, w28P, rbuf_all);     // -> rbuf_all | hpbdot_all
    mfma_reduceF_k<<<dim3(rowsA/128, 1, 8), 256, 0, stream>>>(
        rowsA, av_bf, wA_bf, bias8A, w28A, qbuf_all);     // -> qbuf_all | hbdot_all
    // avU_all[i] = av @ U[i]  (bf16 out direct)
    mfma_nt_k<0, 0, 0, 4, 0, 1><<<dim3(rowsA/64, 4, 4), 256, 0, stream>>>(
        rowsA, LDq, LDq, LDq, (const void*)av_bf, LDq, 0,
        Ut_bf, LDq, (long long)LDq*LDq,
        nullptr, 0, (void*)avU_all_bf, LDq, (long long)rowsA*LDq,
        nullptr, 0, nullptr);

    // ---- fused BIDAT A-chain (MT=4 m-tiles, avU in registers) ----
    bidat_fused_k<<<dim3(2, 4, 128), 256, 0, stream>>>(
        avU_all_bf, pv_bf, rbuf_all, qbuf_all,
        atoms_mask, amino_mask, scoreCp, csump);
    finishC_sm_k<<<128, 128, 0, stream>>>(scoreCp, hbdot_all, battc_b,
                                          atoms_mask, scoreC_all);
    finishP_sm_k<<<128, 256, 0, stream>>>(csump, hpbdot_all, battp_b,
                                          amino_mask, scoreP_all);

    // pooled features (one feat pass feeds all 4 i)
    wsum1B4_k<<<dim3(Bq, 16), 256, 0, stream>>>(av_bf, scoreC_all, wpart, Nq);
    wsum2B_k<<<dim3(Bq, 4), 256, 0, stream>>>(wpart, cf);
    wsum1B4_k<<<dim3(Bq, 16), 256, 0, stream>>>(pv_bf, scoreP_all, wpart, Mq);
    wsum2B_k<<<dim3(Bq, 4), 256, 0, stream>>>(wpart, pf);

    // head
    headlin_k<0><<<dim3(Bq, 4), 256, 0, stream>>>(cf, 4*LDq, 4*LDq,
        combc_W, LDq, combc_b, v1, 770, LDq, 0);
    headlin_k<0><<<dim3(Bq, 4), 256, 0, stream>>>(pf, 4*LDq, 4*LDq,
        combp_W, LDq, combp_b, v1, 770, LDq, 512);
    vfill_k<<<Bq, 256, 0, stream>>>(fps, inv_Temp, Temp, v1);

    headlin_k<1><<<dim3(Bq, 13), 256, 0, stream>>>(v1, 770, 770,
        Wout_W + 0ll*770*770, 770, Wout_b + 0*770, v2, 770, 770, 0);
    headlin_k<1><<<dim3(Bq, 13), 256, 0, stream>>>(v2, 770, 770,
        Wout_W + 1ll*770*770, 770, Wout_b + 1*770, v1, 770, 770, 0);
    headlin_k<1><<<dim3(Bq, 13), 256, 0, stream>>>(v1, 770, 770,
        Wout_W + 2ll*770*770, 770, Wout_b + 2*770, v2, 770, 770, 0);

    final_k<<<Bq, 256, 0, stream>>>(v2, out_W, out_b, out);

    (void)in_sizes; (void)n_in; (void)out_size; (void)ws_size;
    (void)av; (void)pv; (void)bufU; (void)avU_bf; (void)qbuf; (void)csum;
    (void)scoreC; (void)scoreP; (void)h; (void)multi; (void)avp; (void)bufU_all; (void)c1;
}

// Round 22
// 506.760 us; speedup vs baseline: 1.0430x; 1.0129x over previous
//
#include <hip/hip_runtime.h>
#include <math.h>

#define ALPHA_LR 0.2f

#define Bq  32
#define Nq  128
#define Mq  1024
#define CDq 128
#define GDq 64
#define NHq 4
#define LDq 256
#define PDq 40

typedef unsigned short ushort_t;
typedef __attribute__((ext_vector_type(8))) short bf16x8;
typedef __attribute__((ext_vector_type(4))) float f32x4;

__device__ __forceinline__ ushort_t f2bf(float f) {
    union { float f; unsigned u; } x; x.f = f;
    unsigned r = x.u + 0x7FFFu + ((x.u >> 16) & 1u);   // RNE
    return (ushort_t)(r >> 16);
}
__device__ __forceinline__ float bf2f(ushort_t u) {
    union { unsigned u; float f; } x; x.u = ((unsigned)u) << 16;
    return x.f;
}
// fast tanh: 1 - 2*rcp(e^{2x}+1); saturation exact, rel err ~1e-6.
__device__ __forceinline__ float ftanh(float x) {
    float e = __expf(2.f * x);
    return 1.f - 2.f * __builtin_amdgcn_rcpf(e + 1.f);
}

// ---------------------------------------------------------------------------
// MFMA bf16 NT GEMM: C = act(A @ Bt^T + bias); OUTBF=1 writes bf16 directly
// ---------------------------------------------------------------------------
template<int ACT, int MASKED, int HAS_BIAS, int NT, int AF32, int OUTBF>
__global__ __launch_bounds__(256) void mfma_nt_k(
    int M, int N, int K, int Nout,
    const void* __restrict__ Av, int lda, long long sA,
    const ushort_t* __restrict__ Bt, int ldb, long long sB,
    const float* __restrict__ bias, long long sBias,
    void* __restrict__ Cv, int ldc, long long sC,
    const float* __restrict__ maskR, long long sW2,
    const float* __restrict__ maskC)
{
    int z = blockIdx.z;
    Bt += (long long)z * sB;
    if (HAS_BIAS) bias += (long long)z * sBias;
    float* C = nullptr; ushort_t* Cb = nullptr;
    if (OUTBF) Cb = (ushort_t*)Cv + (long long)z * sC;
    else       C  = (float*)Cv + (long long)z * sC;

    int wave = threadIdx.x >> 6;
    int lane = threadIdx.x & 63;
    int lr = lane & 15;
    int kg = lane >> 4;
    int m0 = (blockIdx.x * 4 + wave) * 16;
    int n0 = blockIdx.y * (NT * 16);
    if (m0 >= M) return;

    f32x4 acc[NT];
    #pragma unroll
    for (int t = 0; t < NT; t++) acc[t] = (f32x4){0.f, 0.f, 0.f, 0.f};

    const ushort_t* Ab = nullptr;
    const float*    Af = nullptr;
    if (AF32) Af = (const float*)Av + (long long)z * sA + (long long)(m0 + lr) * lda + kg * 8;
    else      Ab = (const ushort_t*)Av + (long long)z * sA + (long long)(m0 + lr) * lda + kg * 8;
    const ushort_t* Bbase = Bt + (long long)(n0 + lr) * ldb + kg * 8;

    for (int k0 = 0; k0 < K; k0 += 32) {
        bf16x8 a;
        if (AF32) {
            float4 a0 = *(const float4*)(Af + k0);
            float4 a1 = *(const float4*)(Af + k0 + 4);
            a[0] = (short)f2bf(a0.x); a[1] = (short)f2bf(a0.y);
            a[2] = (short)f2bf(a0.z); a[3] = (short)f2bf(a0.w);
            a[4] = (short)f2bf(a1.x); a[5] = (short)f2bf(a1.y);
            a[6] = (short)f2bf(a1.z); a[7] = (short)f2bf(a1.w);
        } else {
            a = *(const bf16x8*)(Ab + k0);
        }
        #pragma unroll
        for (int t = 0; t < NT; t++) {
            bf16x8 b = *(const bf16x8*)(Bbase + (long long)t * 16 * ldb + k0);
            acc[t] = __builtin_amdgcn_mfma_f32_16x16x32_bf16(a, b, acc[t], 0, 0, 0);
        }
    }

    int row0 = m0 + kg * 4;
    #pragma unroll
    for (int t = 0; t < NT; t++) {
        int col = n0 + t * 16 + lr;
        if (col >= Nout) continue;
        float bv = HAS_BIAS ? bias[col] : 0.f;
        float mC = MASKED ? maskC[(long long)z * N + col] : 1.f;
        #pragma unroll
        for (int r = 0; r < 4; r++) {
            float v = acc[t][r] + bv;
            if (ACT == 1) v = v > 0.f ? v : ALPHA_LR * v;
            else if (ACT == 2) v = ftanh(v);
            if (MASKED) v *= maskR[(long long)z * M + row0 + r] * mC;
            if (OUTBF) Cb[(long long)(row0 + r) * ldc + col] = f2bf(v);
            else       C[(long long)(row0 + r) * ldc + col] = v;
        }
    }
}

// ---------------------------------------------------------------------------
// dedicated pv0 GEMM (LDS-staged coalesced fp32 A)
// ---------------------------------------------------------------------------
__global__ __launch_bounds__(256) void pv0_k(
    const float* __restrict__ amino,      // [32768][1024]
    const ushort_t* __restrict__ Bt,      // [48][1024] bf16 (padded)
    const float* __restrict__ bias,       // [40]
    float* __restrict__ C)                // [32768][40]
{
    __shared__ float As[64][68];
    int tid = threadIdx.x;
    int wave = tid >> 6, lane = tid & 63;
    int lr = lane & 15, kg = lane >> 4;
    int m0 = blockIdx.x * 64;

    f32x4 acc[3];
    #pragma unroll
    for (int t = 0; t < 3; t++) acc[t] = (f32x4){0.f, 0.f, 0.f, 0.f};

    int srow = tid >> 2;
    int scol = (tid & 3) * 16;
    const float* srcbase = amino + (long long)(m0 + srow) * 1024 + scol;

    for (int k0 = 0; k0 < 1024; k0 += 64) {
        float4 v0 = *(const float4*)(srcbase + k0);
        float4 v1 = *(const float4*)(srcbase + k0 + 4);
        float4 v2 = *(const float4*)(srcbase + k0 + 8);
        float4 v3 = *(const float4*)(srcbase + k0 + 12);
        *(float4*)&As[srow][scol]      = v0;
        *(float4*)&As[srow][scol + 4]  = v1;
        *(float4*)&As[srow][scol + 8]  = v2;
        *(float4*)&As[srow][scol + 12] = v3;
        __syncthreads();
        #pragma unroll
        for (int ks = 0; ks < 2; ks++) {
            const float* ap = &As[wave * 16 + lr][ks * 32 + kg * 8];
            bf16x8 a;
            #pragma unroll
            for (int j = 0; j < 8; j++) a[j] = (short)f2bf(ap[j]);
            #pragma unroll
            for (int t = 0; t < 3; t++) {
                bf16x8 bfr = *(const bf16x8*)(Bt + (long long)(t * 16 + lr) * 1024 + k0 + ks * 32 + kg * 8);
                acc[t] = __builtin_amdgcn_mfma_f32_16x16x32_bf16(a, bfr, acc[t], 0, 0, 0);
            }
        }
        __syncthreads();
    }
    int row0 = m0 + wave * 16 + kg * 4;
    #pragma unroll
    for (int t = 0; t < 3; t++) {
        int col = t * 16 + lr;
        if (col >= PDq) continue;
        float bv = bias[col];
        #pragma unroll
        for (int r = 0; r < 4; r++)
            C[(long long)(row0 + r) * PDq + col] = acc[t][r] + bv;
    }
}

// ---------------------------------------------------------------------------
// fused reduce GEMM, MT=2 row-tiles per staged weight tile
// ---------------------------------------------------------------------------
__global__ __launch_bounds__(256) void mfma_reduceF_k(
    int M,
    const ushort_t* __restrict__ A,
    const ushort_t* __restrict__ W8,
    const float* __restrict__ bias8,
    const float* __restrict__ w28,
    float* __restrict__ C)
{
    int z = blockIdx.z;
    const ushort_t* W = W8 + (long long)z * 65536;
    const float* bias = bias8 + z * 256;
    const float* w2   = w28 + z * 256;
    float* Cz = C + (long long)z * M;

    __shared__ ushort_t Bs[64 * 256];

    int tid = threadIdx.x;
    int wave = tid >> 6, lane = tid & 63;
    int lr = lane & 15, kg = lane >> 4;
    int m0 = blockIdx.x * 128 + wave * 16;

    const ushort_t* Ab0 = A + (long long)(m0 + lr) * 256 + kg * 8;
    const ushort_t* Ab1 = Ab0 + 64 * 256;
    bf16x8 areg0[8], areg1[8];
    #pragma unroll
    for (int kb = 0; kb < 8; kb++) {
        areg0[kb] = *(const bf16x8*)(Ab0 + kb * 32);
        areg1[kb] = *(const bf16x8*)(Ab1 + kb * 32);
    }

    float rs0[4] = {0.f, 0.f, 0.f, 0.f};
    float rs1[4] = {0.f, 0.f, 0.f, 0.f};

    for (int ph = 0; ph < 4; ph++) {
        int n0 = ph * 64;
        #pragma unroll
        for (int step = 0; step < 8; step++) {
            int g = step * 256 + tid;
            int row = g >> 5, slot = g & 31;
            uint4 v = *(const uint4*)(W + (long long)(n0 + row) * 256 + slot * 8);
            int dst = row * 512 + ((slot * 16) ^ ((row & 31) << 4));
            *(uint4*)((char*)Bs + dst) = v;
        }
        __syncthreads();

        {
            f32x4 acc[4];
            #pragma unroll
            for (int t = 0; t < 4; t++) acc[t] = (f32x4){0.f, 0.f, 0.f, 0.f};
            #pragma unroll
            for (int kb = 0; kb < 8; kb++) {
                #pragma unroll
                for (int t = 0; t < 4; t++) {
                    int rowl = t * 16 + lr;
                    int colb = (kg * 16 + kb * 64) ^ ((rowl & 31) << 4);
                    bf16x8 b = *(const bf16x8*)((char*)Bs + rowl * 512 + colb);
                    acc[t] = __builtin_amdgcn_mfma_f32_16x16x32_bf16(areg0[kb], b, acc[t], 0, 0, 0);
                }
            }
            #pragma unroll
            for (int t = 0; t < 4; t++) {
                int col = n0 + t * 16 + lr;
                float bv = bias[col], wv = w2[col];
                #pragma unroll
                for (int r = 0; r < 4; r++)
                    rs0[r] += ftanh(acc[t][r] + bv) * wv;
            }
        }
        {
            f32x4 acc[4];
            #pragma unroll
            for (int t = 0; t < 4; t++) acc[t] = (f32x4){0.f, 0.f, 0.f, 0.f};
            #pragma unroll
            for (int kb = 0; kb < 8; kb++) {
                #pragma unroll
                for (int t = 0; t < 4; t++) {
                    int rowl = t * 16 + lr;
                    int colb = (kg * 16 + kb * 64) ^ ((rowl & 31) << 4);
                    bf16x8 b = *(const bf16x8*)((char*)Bs + rowl * 512 + colb);
                    acc[t] = __builtin_amdgcn_mfma_f32_16x16x32_bf16(areg1[kb], b, acc[t], 0, 0, 0);
                }
            }
            #pragma unroll
            for (int t = 0; t < 4; t++) {
                int col = n0 + t * 16 + lr;
                float bv = bias[col], wv = w2[col];
                #pragma unroll
                for (int r = 0; r < 4; r++)
                    rs1[r] += ftanh(acc[t][r] + bv) * wv;
            }
        }
        __syncthreads();
    }

    #pragma unroll
    for (int r = 0; r < 4; r++) {
        rs0[r] += __shfl_xor(rs0[r], 1, 64);
        rs0[r] += __shfl_xor(rs0[r], 2, 64);
        rs0[r] += __shfl_xor(rs0[r], 4, 64);
        rs0[r] += __shfl_xor(rs0[r], 8, 64);
        rs1[r] += __shfl_xor(rs1[r], 1, 64);
        rs1[r] += __shfl_xor(rs1[r], 2, 64);
        rs1[r] += __shfl_xor(rs1[r], 4, 64);
        rs1[r] += __shfl_xor(rs1[r], 8, 64);
    }
    if (lr == 0) {
        int row0 = m0 + kg * 4;
        #pragma unroll
        for (int r = 0; r < 4; r++) {
            Cz[row0 + r] = rs0[r];
            Cz[row0 + 64 + r] = rs1[r];
        }
    }
}

// pack biases and w2 vectors for z=8 fused reduce
__global__ __launch_bounds__(256) void pack8_k(
    const float* __restrict__ b1, const float* __restrict__ b2,
    const float* __restrict__ w1, int w1Off,
    const float* __restrict__ w2v, int w2Off,
    float* __restrict__ bias8, float* __restrict__ w28)
{
    int j = blockIdx.x * 256 + threadIdx.x;
    int slot = j >> 8, c = j & 255;
    bias8[j] = slot < 4 ? b1[slot * 256 + c] : b2[(slot - 4) * 256 + c];
    w28[j]   = slot < 4 ? w1[slot * 512 + w1Off + c] : w2v[(slot - 4) * 512 + w2Off + c];
}

// ---------------------------------------------------------------------------
// fused BIDAT A-chain, MT=4 m-tiles, avU in registers
// ---------------------------------------------------------------------------
__global__ __launch_bounds__(256) void bidat_fused_k(
    const ushort_t* __restrict__ avU_all,
    const ushort_t* __restrict__ pv_bf,
    const float* __restrict__ rbuf_all,
    const float* __restrict__ qbuf_all,
    const float* __restrict__ atoms_mask,
    const float* __restrict__ amino_mask,
    float* __restrict__ scoreCp,
    float* __restrict__ csump)
{
    int z = blockIdx.z;
    int i = z >> 5, b = z & 31;
    int gx = blockIdx.x;
    int gy = blockIdx.y;
    int wave = threadIdx.x >> 6;
    int lane = threadIdx.x & 63;
    int lr = lane & 15, kg = lane >> 4;

    int n0 = gx * 64 + wave * 16;
    const ushort_t* Ab = avU_all + ((long long)i * 4096 + (long long)b * 128 + n0 + lr) * 256 + kg * 8;
    bf16x8 areg[8];
    #pragma unroll
    for (int kb = 0; kb < 8; kb++) areg[kb] = *(const bf16x8*)(Ab + kb * 32);

    const float* rI = rbuf_all + (long long)i * 32768 + (long long)b * 1024;
    const float* qI = qbuf_all + (long long)i * 4096 + (long long)b * 128;
    const float* mR = atoms_mask + (long long)b * 128;
    const float* mC = amino_mask + (long long)b * 1024;

    float mRn[4], qn[4];
    #pragma unroll
    for (int r = 0; r < 4; r++) {
        int n = n0 + kg * 4 + r;
        mRn[r] = mR[n];
        qn[r]  = qI[n];
    }

    float sc[4] = {0.f, 0.f, 0.f, 0.f};
    __shared__ float cl[4][64];

    for (int mt = 0; mt < 4; mt++) {
        int m0 = (gy * 4 + mt) * 64;
        const ushort_t* Bb = pv_bf + ((long long)b * 1024 + m0 + lr) * 256 + kg * 8;

        f32x4 acc[4];
        #pragma unroll
        for (int t = 0; t < 4; t++) acc[t] = (f32x4){0.f, 0.f, 0.f, 0.f};
        #pragma unroll
        for (int kb = 0; kb < 8; kb++) {
            #pragma unroll
            for (int t = 0; t < 4; t++) {
                bf16x8 bfr = *(const bf16x8*)(Bb + (long long)t * 16 * 256 + kb * 32);
                acc[t] = __builtin_amdgcn_mfma_f32_16x16x32_bf16(areg[kb], bfr, acc[t], 0, 0, 0);
            }
        }

        float cs[4] = {0.f, 0.f, 0.f, 0.f};
        #pragma unroll
        for (int t = 0; t < 4; t++) {
            int m = m0 + t * 16 + lr;
            float mc = mC[m];
            float rv = rI[m];
            #pragma unroll
            for (int r = 0; r < 4; r++) {
                float a = ftanh(acc[t][r]) * mRn[r] * mc;
                sc[r] += a * rv;
                cs[t] += a * qn[r];
            }
        }
        #pragma unroll
        for (int t = 0; t < 4; t++) {
            cs[t] += __shfl_xor(cs[t], 16, 64);
            cs[t] += __shfl_xor(cs[t], 32, 64);
        }
        __syncthreads();
        if (kg == 0) {
            #pragma unroll
            for (int t = 0; t < 4; t++) cl[wave][t * 16 + lr] = cs[t];
        }
        __syncthreads();
        if (threadIdx.x < 64) {
            float s = cl[0][threadIdx.x] + cl[1][threadIdx.x]
                    + cl[2][threadIdx.x] + cl[3][threadIdx.x];
            csump[((long long)z * 2 + gx) * 1024 + m0 + threadIdx.x] = s;
        }
    }

    #pragma unroll
    for (int r = 0; r < 4; r++) {
        sc[r] += __shfl_xor(sc[r], 1, 64);
        sc[r] += __shfl_xor(sc[r], 2, 64);
        sc[r] += __shfl_xor(sc[r], 4, 64);
        sc[r] += __shfl_xor(sc[r], 8, 64);
    }
    if (lr == 0) {
        #pragma unroll
        for (int r = 0; r < 4; r++) {
            int n = gx * 64 + wave * 16 + kg * 4 + r;
            scoreCp[((long long)z * 4 + gy) * 128 + n] = sc[r];
        }
    }
}

// finishC + masked softmax fused
__global__ __launch_bounds__(128) void finishC_sm_k(
    const float* __restrict__ scoreCp, const float* __restrict__ hbdot_all,
    const float* __restrict__ battc_b, const float* __restrict__ mask,
    float* __restrict__ scoreC_all)
{
    int z = blockIdx.x;
    int i = z >> 5, b = z & 31;
    int n = threadIdx.x;
    __shared__ float red[128];
    float s = 0.f;
    #pragma unroll
    for (int gy = 0; gy < 4; gy++)
        s += scoreCp[((long long)z * 4 + gy) * 128 + n];
    s += hbdot_all[(long long)i * 4096 + b * 128 + n] + battc_b[i];
    red[n] = s; __syncthreads();
    for (int off = 64; off > 0; off >>= 1) {
        if (n < off) red[n] = fmaxf(red[n], red[n + off]);
        __syncthreads();
    }
    float mx = red[0];
    __syncthreads();
    float e = __expf(s - mx) * mask[(long long)b * 128 + n];
    red[n] = e; __syncthreads();
    for (int off = 64; off > 0; off >>= 1) {
        if (n < off) red[n] += red[n + off];
        __syncthreads();
    }
    float inv = 1.0f / (red[0] + 1e-6f);
    scoreC_all[(long long)z * 128 + n] = e * inv;
}

// finishP + masked softmax fused
__global__ __launch_bounds__(256) void finishP_sm_k(
    const float* __restrict__ csump, const float* __restrict__ hpbdot_all,
    const float* __restrict__ battp_b, const float* __restrict__ mask,
    float* __restrict__ scoreP_all)
{
    int z = blockIdx.x;
    int i = z >> 5, b = z & 31;
    int t = threadIdx.x;
    __shared__ float red[256];
    float vals[4];
    float mx = -1e30f;
    #pragma unroll
    for (int j = 0; j < 4; j++) {
        int m = j * 256 + t;
        float s = csump[((long long)z * 2 + 0) * 1024 + m]
                + csump[((long long)z * 2 + 1) * 1024 + m]
                + hpbdot_all[(long long)i * 32768 + (long long)b * 1024 + m]
                + battp_b[i];
        vals[j] = s;
        mx = fmaxf(mx, s);
    }
    red[t] = mx; __syncthreads();
    for (int off = 128; off > 0; off >>= 1) {
        if (t < off) red[t] = fmaxf(red[t], red[t + off]);
        __syncthreads();
    }
    mx = red[0];
    __syncthreads();
    float sum = 0.f;
    #pragma unroll
    for (int j = 0; j < 4; j++) {
        float e = __expf(vals[j] - mx) * mask[(long long)b * 1024 + j * 256 + t];
        vals[j] = e; sum += e;
    }
    red[t] = sum; __syncthreads();
    for (int off = 128; off > 0; off >>= 1) {
        if (t < off) red[t] += red[t + off];
        __syncthreads();
    }
    float inv = 1.0f / (red[0] + 1e-6f);
    #pragma unroll
    for (int j = 0; j < 4; j++)
        scoreP_all[(long long)z * 1024 + j * 256 + t] = vals[j] * inv;
}

// fp32 [rows][Ksrc] -> bf16 [rows][Kdst] zero-padded (atoms_emb only)
__global__ __launch_bounds__(256) void cvtpad_bf16_k(
    const float* __restrict__ in, ushort_t* __restrict__ out,
    int rows, int Ksrc, int Kdst)
{
    long long idx = (long long)blockIdx.x * 256 + threadIdx.x;
    long long total = (long long)rows * Kdst;
    if (idx >= total) return;
    int r = (int)(idx / Kdst), k = (int)(idx % Kdst);
    out[idx] = (k < Ksrc) ? f2bf(in[(long long)r * Ksrc + k]) : (ushort_t)0;
}

// ---------------------------------------------------------------------------
// all weight transpose-converts in one table-driven launch
// ---------------------------------------------------------------------------
struct WtEnt {
    const float* W; ushort_t* Wt;
    int K, Nsrc, Npad, Kp, zcnt, blkStart;
};
struct WtTab { WtEnt e[11]; };

__global__ __launch_bounds__(256) void wtcvtAll_k(WtTab tab)
{
    int blk = blockIdx.x;
    int ei = 0;
    #pragma unroll
    for (int i = 1; i < 11; i++) if (blk >= tab.e[i].blkStart) ei = i;
    WtEnt E = tab.e[ei];
    long long perZ = (long long)E.Npad * E.Kp;
    long long lidx = (long long)(blk - E.blkStart) * 256 + threadIdx.x;
    if (lidx >= perZ * E.zcnt) return;
    int z = (int)(lidx / perZ);
    long long idx = lidx % perZ;
    int n = (int)(idx / E.Kp), k = (int)(idx % E.Kp);
    const float* Wz = E.W + (long long)z * E.K * E.Nsrc;
    ushort_t* Oz = E.Wt + (long long)z * perZ;
    float v = (k < E.K && n < E.Nsrc) ? Wz[(long long)k * E.Nsrc + n] : 0.f;
    Oz[idx] = f2bf(v);
}

// per-row GAT source/dest attention logits
__global__ __launch_bounds__(128) void gat_e_k(
    const float* __restrict__ Wh, int ldWh, int GD,
    const float* __restrict__ a, int aStride,
    float* __restrict__ esrc, float* __restrict__ edst, int rows)
{
    int row = blockIdx.x;
    int k = blockIdx.y;
    int g = threadIdx.x;
    float ws = 0.f, wd = 0.f;
    if (g < GD) {
        float wv = Wh[(long long)row * ldWh + k * GD + g];
        ws = wv * a[k * aStride + g];
        wd = wv * a[k * aStride + GD + g];
    }
    __shared__ float sb[2][128];
    sb[0][threadIdx.x] = ws; sb[1][threadIdx.x] = wd;
    __syncthreads();
    for (int off = 64; off > 0; off >>= 1) {
        if (threadIdx.x < off) {
            sb[0][threadIdx.x] += sb[0][threadIdx.x + off];
            sb[1][threadIdx.x] += sb[1][threadIdx.x + off];
        }
        __syncthreads();
    }
    if (threadIdx.x == 0) {
        esrc[(long long)k * rows + row] = sb[0][0];
        edst[(long long)k * rows + row] = sb[1][0];
    }
}

// ---------------------------------------------------------------------------
// GAT attention, 256-thread blocks, bf16 output
// ---------------------------------------------------------------------------
template<int GD>
__global__ __launch_bounds__(256) void gat_attn2_k(
    const float* __restrict__ Wh, int ldWh,
    const int* __restrict__ adj,
    const float* __restrict__ esrc, const float* __restrict__ edst,
    ushort_t* __restrict__ outp, int ldOut)
{
    int row = blockIdx.x;          // b*N + n
    int k = blockIdx.y;
    int rows = gridDim.x;
    int b = row >> 7, n = row & 127;
    int tid = threadIdx.x;

    __shared__ float att[128];
    __shared__ float red[128];
    __shared__ float sred[256];

    if (tid < 128) {
        float e = esrc[(long long)k * rows + row] + edst[(long long)k * rows + b * 128 + tid];
        e = e > 0.f ? e : ALPHA_LR * e;
        if (adj[(long long)b * 16384 + n * 128 + tid] <= 0) e = -9.0e15f;
        att[tid] = e;
        red[tid] = e;
    }
    __syncthreads();
    for (int off = 64; off > 0; off >>= 1) {
        if (tid < off) red[tid] = fmaxf(red[tid], red[tid + off]);
        __syncthreads();
    }
    float mx = red[0];
    __syncthreads();
    if (tid < 128) {
        float ex = __expf(att[tid] - mx);
        att[tid] = ex;
        red[tid] = ex;
    }
    __syncthreads();
    for (int off = 64; off > 0; off >>= 1) {
        if (tid < off) red[tid] += red[tid + off];
        __syncthreads();
    }
    float inv = 1.0f / red[0];
    __syncthreads();

    constexpr int SPLIT = 256 / GD;
    constexpr int CH = 128 / SPLIT;
    int g = tid % GD;
    int part = tid / GD;
    const float* Whb = Wh + (long long)(b * 128) * ldWh + k * GD + g;
    float s = 0.f;
    int mm0 = part * CH;
    for (int mm = mm0; mm < mm0 + CH; mm++)
        s += att[mm] * Whb[(long long)mm * ldWh];
    sred[part * GD + g] = s;
    __syncthreads();
    if (part == 0) {
        float tot = s;
        #pragma unroll
        for (int p = 1; p < SPLIT; p++) tot += sred[p * GD + g];
        tot *= inv;
        tot = tot > 0.f ? tot : expm1f(tot);   // ELU
        outp[(long long)row * ldOut + k * GD + g] = f2bf(tot);
    }
}

// ---------------------------------------------------------------------------
// fused 3x 11x11 conv chain, fully LDS-resident
// ---------------------------------------------------------------------------
__global__ __launch_bounds__(256) void conv3_k(
    const float* __restrict__ x,        // [32][1024][40] (pv0 out)
    const float* __restrict__ Wc,       // [3][121]
    const float* __restrict__ bc,       // [3]
    ushort_t* __restrict__ y)           // [32768][64] bf16, d>=40 zero
{
    __shared__ float wsh[3][121];
    __shared__ float A[94][50];
    __shared__ float Bv[84][50];
    __shared__ float Cv[74][50];

    int tid = threadIdx.x;
    int b = blockIdx.y;
    int m0 = blockIdx.x * 64;

    for (int i = tid; i < 363; i += 256) wsh[i / 121][i % 121] = Wc[i];
    const float* xb = x + (long long)b * Mq * PDq;
    for (int idx = tid; idx < 94 * 50; idx += 256) {
        int row = idx / 50, col = idx % 50;
        int gm = m0 - 15 + row, d = col - 5;
        float v = 0.f;
        if (d >= 0 && d < PDq && gm >= 0 && gm < Mq)
            v = xb[(long long)gm * PDq + d];
        A[row][col] = v;
    }
    __syncthreads();

    {
        float b0 = bc[0];
        for (int idx = tid; idx < 84 * 50; idx += 256) {
            int row = idx / 50, col = idx % 50;
            float s = 0.f;
            if (col >= 5 && col < 45) {
                int d = col - 5;
                #pragma unroll
                for (int i = 0; i < 11; i++)
                    #pragma unroll
                    for (int j = 0; j < 11; j++)
                        s += A[row + i][d + j] * wsh[0][i * 11 + j];
                s += b0;
                s = s > 0.f ? s : ALPHA_LR * s;
            }
            Bv[row][col] = s;
        }
    }
    __syncthreads();

    {
        float b1 = bc[1];
        for (int idx = tid; idx < 74 * 50; idx += 256) {
            int row = idx / 50, col = idx % 50;
            float s = 0.f;
            if (col >= 5 && col < 45) {
                int d = col - 5;
                #pragma unroll
                for (int i = 0; i < 11; i++)
                    #pragma unroll
                    for (int j = 0; j < 11; j++)
                        s += Bv[row + i][d + j] * wsh[1][i * 11 + j];
                s += b1;
                s = s > 0.f ? s : ALPHA_LR * s;
            }
            Cv[row][col] = s;
        }
    }
    __syncthreads();

    {
        float b2 = bc[2];
        for (int idx = tid; idx < 64 * 64; idx += 256) {
            int row = idx / 64, d = idx % 64;
            long long o = ((long long)b * Mq + m0 + row) * 64 + d;
            if (d >= PDq) { y[o] = 0; continue; }
            float s = 0.f;
            #pragma unroll
            for (int i = 0; i < 11; i++)
                #pragma unroll
                for (int j = 0; j < 11; j++)
                    s += Cv[row + i][d + j] * wsh[2][i * 11 + j];
            s += b2;
            s = s > 0.f ? s : ALPHA_LR * s;
            y[o] = f2bf(s);
        }
    }
}

// ---------------------------------------------------------------------------
// r22: both weighted-sum stage-1 passes in ONE launch (blockIdx.z selects
// side). Identical per-element arithmetic & summation order as wsum1B4_k.
// ---------------------------------------------------------------------------
__global__ __launch_bounds__(256) void wsum1B4B_k(
    const ushort_t* __restrict__ featC, const float* __restrict__ attC,
    float* __restrict__ partC,
    const ushort_t* __restrict__ featP, const float* __restrict__ attP,
    float* __restrict__ partP)
{
    int side = blockIdx.z;
    const ushort_t* feat = side ? featP : featC;
    const float* att_all = side ? attP : attC;
    float* partial       = side ? partP : partC;
    int L                = side ? Mq : Nq;

    int b = blockIdx.x, c = blockIdx.y, l = threadIdx.x;
    int chunk = L / 16;
    const ushort_t* fb = feat + (long long)b * L * LDq;
    const float* a0 = att_all + ((long long)0 * Bq + b) * L;
    const float* a1 = att_all + ((long long)1 * Bq + b) * L;
    const float* a2 = att_all + ((long long)2 * Bq + b) * L;
    const float* a3 = att_all + ((long long)3 * Bq + b) * L;
    float s0 = 0.f, s1 = 0.f, s2 = 0.f, s3 = 0.f;
    int r0 = c * chunk, r1 = r0 + chunk;
    for (int r = r0; r < r1; r++) {
        float f = bf2f(fb[(long long)r * LDq + l]);
        s0 += f * a0[r]; s1 += f * a1[r];
        s2 += f * a2[r]; s3 += f * a3[r];
    }
    partial[(((long long)0 * Bq + b) * 16 + c) * LDq + l] = s0;
    partial[(((long long)1 * Bq + b) * 16 + c) * LDq + l] = s1;
    partial[(((long long)2 * Bq + b) * 16 + c) * LDq + l] = s2;
    partial[(((long long)3 * Bq + b) * 16 + c) * LDq + l] = s3;
}

// ---------------------------------------------------------------------------
// head layer reading wsum partials directly (r19-verified; kills wsum2B)
// vin[j] = sum_{c=0..15} partial[((j/256)*Bq+b)*16+c)*256 + j%256]
// (same c-order as wsum2B -> bit-identical)
// ---------------------------------------------------------------------------
__global__ __launch_bounds__(256) void headlinP_k(
    const float* __restrict__ partial,
    const float* __restrict__ W, int ldw,
    const float* __restrict__ bias,
    float* __restrict__ vout, int ldo, int OD, int colBase)
{
    int b = blockIdx.x;
    int c = threadIdx.x & 63;
    int s = threadIdx.x >> 6;
    int col = blockIdx.y * 64 + c;

    __shared__ float vs[1024];
    for (int j = threadIdx.x; j < 1024; j += 256) {
        int i = j >> 8, l = j & 255;
        const float* pbase = partial + (((long long)i * Bq + b) * 16) * LDq + l;
        float acc = 0.f;
        #pragma unroll
        for (int cc = 0; cc < 16; cc++) acc += pbase[cc * LDq];
        vs[j] = acc;
    }
    __syncthreads();

    float sum = 0.f;
    if (col < OD) {
        int k0 = 256 * s, k1 = 256 * (s + 1);
        #pragma unroll 4
        for (int k = k0; k < k1; k++)
            sum += vs[k] * W[(long long)k * ldw + col];
    }
    __shared__ float red[4][64];
    red[s][c] = sum;
    __syncthreads();
    if (s == 0 && col < OD) {
        float t = red[0][c] + red[1][c] + red[2][c] + red[3][c] + bias[col];
        vout[(long long)b * ldo + colBase + col] = t;
    }
}

// Skinny dense layer for the head (fp32 vin)
template<int ACT>
__global__ __launch_bounds__(256) void headlin_k(
    const float* __restrict__ vin, int ldv, int VD,
    const float* __restrict__ W, int ldw,
    const float* __restrict__ bias,
    float* __restrict__ vout, int ldo, int OD, int colBase)
{
    int b = blockIdx.x;
    int c = threadIdx.x & 63;
    int s = threadIdx.x >> 6;
    int col = blockIdx.y * 64 + c;

    __shared__ float vs[1024];
    for (int i = threadIdx.x; i < VD; i += 256) vs[i] = vin[(long long)b * ldv + i];
    __syncthreads();

    float sum = 0.f;
    if (col < OD) {
        int k0 = (VD * s) >> 2, k1 = (VD * (s + 1)) >> 2;
        #pragma unroll 4
        for (int k = k0; k < k1; k++)
            sum += vs[k] * W[(long long)k * ldw + col];
    }
    __shared__ float red[4][64];
    red[s][c] = sum;
    __syncthreads();
    if (s == 0 && col < OD) {
        float t = red[0][c] + red[1][c] + red[2][c] + red[3][c] + bias[col];
        if (ACT == 1) t = t > 0.f ? t : ALPHA_LR * t;
        vout[(long long)b * ldo + colBase + col] = t;
    }
}

// v[b,256:512]=fps, v[b,768]=invT, v[b,769]=T
__global__ __launch_bounds__(256) void vfill_k(
    const float* __restrict__ fps, const float* __restrict__ invT,
    const float* __restrict__ T, float* __restrict__ v)
{
    int b = blockIdx.x, t = threadIdx.x;
    v[(long long)b * 770 + 256 + t] = fps[(long long)b * 256 + t];
    if (t == 0) {
        v[(long long)b * 770 + 768] = invT[b];
        v[(long long)b * 770 + 769] = T[b];
    }
}

// out[b] = v[b,:770]·W + b
__global__ __launch_bounds__(256) void final_k(
    const float* __restrict__ v, const float* __restrict__ W,
    const float* __restrict__ bptr, float* __restrict__ out)
{
    int b = blockIdx.x, t = threadIdx.x;
    float s = 0.f;
    for (int i = t; i < 770; i += 256) s += v[(long long)b * 770 + i] * W[i];
    __shared__ float red[256];
    red[t] = s; __syncthreads();
    for (int off = 128; off > 0; off >>= 1) {
        if (t < off) red[t] += red[t + off];
        __syncthreads();
    }
    if (t == 0) out[b] = red[0] + bptr[0];
}

extern "C" void kernel_launch(void* const* d_in, const int* in_sizes, int n_in,
                              void* d_out, int out_size, void* d_ws, size_t ws_size,
                              hipStream_t stream)
{
    const float* atoms_emb = (const float*)d_in[0];
    const int*   adjacency = (const int*)d_in[1];
    const float* atoms_mask= (const float*)d_in[2];
    const float* amino_emb = (const float*)d_in[3];
    const float* amino_mask= (const float*)d_in[4];
    const float* fps       = (const float*)d_in[5];
    const float* inv_Temp  = (const float*)d_in[6];
    const float* Temp      = (const float*)d_in[7];
    const float* bert_W    = (const float*)d_in[8];
    const float* bert_b    = (const float*)d_in[9];
    const float* gat_W     = (const float*)d_in[10];
    const float* gat_a     = (const float*)d_in[11];
    const float* gatout_W  = (const float*)d_in[12];
    const float* gatout_a  = (const float*)d_in[13];
    const float* Wcomp_W   = (const float*)d_in[14];
    const float* Wcomp_b   = (const float*)d_in[15];
    const float* prot_W    = (const float*)d_in[16];
    const float* prot_b    = (const float*)d_in[17];
    const float* conv_W    = (const float*)d_in[18];
    const float* conv_b    = (const float*)d_in[19];
    const float* Wprot_W   = (const float*)d_in[20];
    const float* Wprot_b   = (const float*)d_in[21];
    const float* U         = (const float*)d_in[22];
    const float* tc2p_W    = (const float*)d_in[23];
    const float* tc2p_b    = (const float*)d_in[24];
    const float* tp2c_W    = (const float*)d_in[25];
    const float* tp2c_b    = (const float*)d_in[26];
    const float* bhc_W     = (const float*)d_in[27];
    const float* bhc_b     = (const float*)d_in[28];
    const float* bhp_W     = (const float*)d_in[29];
    const float* bhp_b     = (const float*)d_in[30];
    const float* battc_W   = (const float*)d_in[31];
    const float* battc_b   = (const float*)d_in[32];
    const float* battp_W   = (const float*)d_in[33];
    const float* battp_b   = (const float*)d_in[34];
    const float* combc_W   = (const float*)d_in[35];
    const float* combc_b   = (const float*)d_in[36];
    const float* combp_W   = (const float*)d_in[37];
    const float* combp_b   = (const float*)d_in[38];
    const float* Wout_W    = (const float*)d_in[39];
    const float* Wout_b    = (const float*)d_in[40];
    const float* out_W     = (const float*)d_in[41];
    const float* out_b     = (const float*)d_in[42];
    float* out = (float*)d_out;

    // ---- workspace layout (floats) ----
    float* w = (float*)d_ws;
    float* av    = w; w += (long long)Bq*Nq*LDq;
    float* pv    = w; w += (long long)Bq*Mq*LDq;
    float* sx    = w; w += (long long)Bq*Mq*LDq;   // early fp32 scratch -> precomp pool
    float* pool  = w; w += (long long)Bq*Nq*Mq;    // early bf16 staging -> partials
    float* bufU  = w; w += (long long)Bq*Nq*LDq;   // wsum partials (P side)
    float* bufTC = w; w += (long long)Bq*Nq*LDq;   // wsum partials (C side)
    float* esrc  = w; w += (long long)NHq*Bq*Nq;
    float* edst  = w; w += (long long)NHq*Bq*Nq;
    float* scoreC= w; w += (long long)Bq*Nq;
    float* scoreP= w; w += (long long)Bq*Mq;
    float* rbuf  = w; w += (long long)Bq*Mq;       // -> pack8 outputs
    float* qbuf  = w; w += (long long)Bq*Nq;
    float* csum  = w; w += (long long)Bq*Mq;
    float* cf    = w; w += (long long)Bq*4*LDq;
    float* pf    = w; w += (long long)Bq*4*LDq;
    float* v1    = w; w += (long long)Bq*770;
    float* v2    = w; w += (long long)Bq*770;
    // bf16 buffers
    ushort_t* pv_bf  = (ushort_t*)w; w += (long long)Bq*Mq*LDq/2;
    ushort_t* av_bf  = (ushort_t*)w; w += (long long)Bq*Nq*LDq/2;
    ushort_t* avU_bf = (ushort_t*)w; w += (long long)Bq*Nq*LDq/2;
    ushort_t* Ut_bf     = (ushort_t*)w; w += (long long)4*LDq*LDq/2;
    ushort_t* protWt_bf = (ushort_t*)w; w += (long long)48*1024/2;
    ushort_t* bertWt_bf = (ushort_t*)w; w += (long long)128*320/2;
    ushort_t* gatWt_bf  = (ushort_t*)w; w += (long long)4*64*128/2;
    ushort_t* gatoutWt_bf=(ushort_t*)w; w += (long long)128*256/2;
    ushort_t* WcompT_bf = (ushort_t*)w; w += (long long)256*128/2;
    ushort_t* WprotT_bf = (ushort_t*)w; w += (long long)256*64/2;
    ushort_t* wP_bf     = (ushort_t*)w; w += (long long)8*256*256/2;
    ushort_t* wA_bf     = (ushort_t*)w; w += (long long)8*256*256/2;

    int rowsA = Bq * Nq;     // 4096
    int rowsP = Bq * Mq;     // 32768

    // early fp32 aliases inside sx (dead before BIDAT precompute)
    float* h     = sx;
    float* WhAll = h + (long long)rowsA*CDq;
    float* multi = WhAll + (long long)rowsA*NHq*GDq;
    float* Wh2   = multi + (long long)rowsA*NHq*GDq;
    float* avp   = Wh2 + (long long)rowsA*CDq;
    float* c0    = avp + (long long)rowsA*CDq;
    float* c1    = c0 + (long long)rowsP*PDq;

    // early bf16 aliases inside pool (dead before partials phase)
    ushort_t* atoms_bf = (ushort_t*)pool;
    ushort_t* h_bf     = atoms_bf + (long long)rowsA*320;
    ushort_t* multi_bf = h_bf + (long long)rowsA*128;
    ushort_t* avp_bf   = multi_bf + (long long)rowsA*256;
    ushort_t* c1_bf    = avp_bf + (long long)rowsA*128;

    // BIDAT-precompute pool in sx (z=8 reduce outputs land contiguously)
    float*    rbuf_all   = sx;
    float*    hpbdot_all = rbuf_all   + (long long)4*rowsP;
    float*    qbuf_all   = hpbdot_all + (long long)4*rowsP;
    float*    hbdot_all  = qbuf_all   + (long long)4*rowsA;
    float*    bufU_all   = hbdot_all  + (long long)4*rowsA;
    ushort_t* avU_all_bf = (ushort_t*)(bufU_all + (long long)4*rowsA*LDq);

    // partials pool (after bidat)
    float* scoreCp    = pool;                        // 128*4*128
    float* csump      = scoreCp + 65536;             // 128*2*1024
    float* scoreC_all = csump + 262144;              // 16384
    float* scoreP_all = scoreC_all + 16384;          // 131072

    float* wpartC = bufTC;   // C-side wsum partials
    float* wpartP = bufU;    // P-side wsum partials

    // pack8 outputs
    float* bias8P = rbuf;
    float* w28P   = rbuf + 2048;
    float* bias8A = rbuf + 4096;
    float* w28A   = rbuf + 6144;

    // ---- single table-driven weight convert launch ----
    WtTab tab;
    int blk = 0;
    auto setent = [&](int i, const float* W, ushort_t* Wt,
                      int K, int Nsrc, int Npad, int Kp, int zc) {
        tab.e[i].W = W; tab.e[i].Wt = Wt;
        tab.e[i].K = K; tab.e[i].Nsrc = Nsrc; tab.e[i].Npad = Npad;
        tab.e[i].Kp = Kp; tab.e[i].zcnt = zc; tab.e[i].blkStart = blk;
        blk += (int)(((long long)zc * Npad * Kp + 255) / 256);
    };
    setent(0,  U,        Ut_bf,       256, 256, 256, 256, 4);
    setent(1,  prot_W,   protWt_bf,   1024, 40, 48, 1024, 1);
    setent(2,  bert_W,   bertWt_bf,   300, 128, 128, 320, 1);
    setent(3,  gat_W,    gatWt_bf,    128, 64,  64,  128, 4);
    setent(4,  gatout_W, gatoutWt_bf, 256, 128, 128, 256, 1);
    setent(5,  Wcomp_W,  WcompT_bf,   128, 256, 256, 128, 1);
    setent(6,  Wprot_W,  WprotT_bf,   40,  256, 256, 64,  1);
    setent(7,  tp2c_W,   wP_bf,              256, 256, 256, 256, 4);
    setent(8,  bhp_W,    wP_bf + 4*65536,    256, 256, 256, 256, 4);
    setent(9,  tc2p_W,   wA_bf,              256, 256, 256, 256, 4);
    setent(10, bhc_W,    wA_bf + 4*65536,    256, 256, 256, 256, 4);
    wtcvtAll_k<<<blk, 256, 0, stream>>>(tab);
    pack8_k<<<8, 256, 0, stream>>>(tp2c_b, bhp_b, battc_W, 256, battp_W, 0, bias8P, w28P);
    pack8_k<<<8, 256, 0, stream>>>(tc2p_b, bhc_b, battp_W, 256, battc_W, 0, bias8A, w28A);

    // 1. h = atoms_emb @ bert_W + bert_b  (MFMA, K padded, bf16 out direct)
    cvtpad_bf16_k<<<(int)(((long long)rowsA*320 + 255)/256), 256, 0, stream>>>(
        atoms_emb, atoms_bf, rowsA, 300, 320);
    mfma_nt_k<0, 0, 1, 2, 0, 1><<<dim3(rowsA/64, 4, 1), 256, 0, stream>>>(
        rowsA, CDq, 320, CDq, (const void*)atoms_bf, 320, 0,
        bertWt_bf, 320, 0, bert_b, 0, (void*)h_bf, CDq, 0, nullptr, 0, nullptr);

    // 2. Wh_all = h @ gat_W[k]  (MFMA, z=4, fp32 out for gat_e)
    mfma_nt_k<0, 0, 0, 4, 0, 0><<<dim3(rowsA/64, 1, 4), 256, 0, stream>>>(
        rowsA, GDq, CDq, GDq, (const void*)h_bf, CDq, 0,
        gatWt_bf, CDq, (long long)GDq*CDq,
        nullptr, 0, (void*)WhAll, NHq*GDq, GDq, nullptr, 0, nullptr);

    // 3-4. GAT heads -> multi_bf (ELU, bf16 out direct)
    gat_e_k<<<dim3(rowsA, NHq), 128, 0, stream>>>(WhAll, NHq*GDq, GDq, gat_a, 2*GDq,
                                                  esrc, edst, rowsA);
    gat_attn2_k<64><<<dim3(rowsA, NHq), 256, 0, stream>>>(WhAll, NHq*GDq, adjacency,
                                                          esrc, edst, multi_bf, NHq*GDq);

    // 5-7. GAT out layer -> avp_bf (ELU)
    mfma_nt_k<0, 0, 0, 2, 0, 0><<<dim3(rowsA/64, 4, 1), 256, 0, stream>>>(
        rowsA, CDq, 256, CDq, (const void*)multi_bf, 256, 0,
        gatoutWt_bf, 256, 0, nullptr, 0, (void*)Wh2, CDq, 0, nullptr, 0, nullptr);
    gat_e_k<<<dim3(rowsA, 1), 128, 0, stream>>>(Wh2, CDq, CDq, gatout_a, 2*CDq,
                                                esrc, edst, rowsA);
    gat_attn2_k<128><<<dim3(rowsA, 1), 256, 0, stream>>>(Wh2, CDq, adjacency,
                                                         esrc, edst, avp_bf, CDq);

    // 8. av = leaky(avp @ Wcomp_W + b)  (MFMA, bf16 out direct)
    mfma_nt_k<1, 0, 1, 4, 0, 1><<<dim3(rowsA/64, 4, 1), 256, 0, stream>>>(
        rowsA, LDq, CDq, LDq, (const void*)avp_bf, CDq, 0,
        WcompT_bf, CDq, 0, Wcomp_b, 0, (void*)av_bf, LDq, 0, nullptr, 0, nullptr);

    // 9. pv0 = amino_emb @ prot_W + b  (LDS-staged coalesced kernel)
    pv0_k<<<rowsP/64, 256, 0, stream>>>(amino_emb, protWt_bf, prot_b, c0);

    // 10. fused 3x conv chain, LDS-resident, bf16 padded out
    conv3_k<<<dim3(Mq/64, Bq), 256, 0, stream>>>(c0, conv_W, conv_b, c1_bf);

    // 11. pv = leaky(x @ Wprot_W + b)  (MFMA, bf16 out direct)
    mfma_nt_k<1, 0, 1, 4, 0, 1><<<dim3(rowsP/64, 4, 1), 256, 0, stream>>>(
        rowsP, LDq, 64, LDq, (const void*)c1_bf, 64, 0,
        WprotT_bf, 64, 0, Wprot_b, 0, (void*)pv_bf, LDq, 0, nullptr, 0, nullptr);

    // ---- BIDAT precompute: fused z=8 reduces (MT=2 row-tiles) ----
    mfma_reduceF_k<<<dim3(rowsP/128, 1, 8), 256, 0, stream>>>(
        rowsP, pv_bf, wP_bf, bias8P, w28P, rbuf_all);     // -> rbuf_all | hpbdot_all
    mfma_reduceF_k<<<dim3(rowsA/128, 1, 8), 256, 0, stream>>>(
        rowsA, av_bf, wA_bf, bias8A, w28A, qbuf_all);     // -> qbuf_all | hbdot_all
    // avU_all[i] = av @ U[i]  (bf16 out direct)
    mfma_nt_k<0, 0, 0, 4, 0, 1><<<dim3(rowsA/64, 4, 4), 256, 0, stream>>>(
        rowsA, LDq, LDq, LDq, (const void*)av_bf, LDq, 0,
        Ut_bf, LDq, (long long)LDq*LDq,
        nullptr, 0, (void*)avU_all_bf, LDq, (long long)rowsA*LDq,
        nullptr, 0, nullptr);

    // ---- fused BIDAT A-chain (MT=4 m-tiles, avU in registers) ----
    bidat_fused_k<<<dim3(2, 4, 128), 256, 0, stream>>>(
        avU_all_bf, pv_bf, rbuf_all, qbuf_all,
        atoms_mask, amino_mask, scoreCp, csump);
    finishC_sm_k<<<128, 128, 0, stream>>>(scoreCp, hbdot_all, battc_b,
                                          atoms_mask, scoreC_all);
    finishP_sm_k<<<128, 256, 0, stream>>>(csump, hpbdot_all, battp_b,
                                          amino_mask, scoreP_all);

    // pooled features: both stage-1 passes in one launch (r22)
    wsum1B4B_k<<<dim3(Bq, 16, 2), 256, 0, stream>>>(
        av_bf, scoreC_all, wpartC, pv_bf, scoreP_all, wpartP);

    // head (headlinP reads partials directly; r19-verified)
    headlinP_k<<<dim3(Bq, 4), 256, 0, stream>>>(wpartC,
        combc_W, LDq, combc_b, v1, 770, LDq, 0);
    headlinP_k<<<dim3(Bq, 4), 256, 0, stream>>>(wpartP,
        combp_W, LDq, combp_b, v1, 770, LDq, 512);
    vfill_k<<<Bq, 256, 0, stream>>>(fps, inv_Temp, Temp, v1);

    headlin_k<1><<<dim3(Bq, 13), 256, 0, stream>>>(v1, 770, 770,
        Wout_W + 0ll*770*770, 770, Wout_b + 0*770, v2, 770, 770, 0);
    headlin_k<1><<<dim3(Bq, 13), 256, 0, stream>>>(v2, 770, 770,
        Wout_W + 1ll*770*770, 770, Wout_b + 1*770, v1, 770, 770, 0);
    headlin_k<1><<<dim3(Bq, 13), 256, 0, stream>>>(v1, 770, 770,
        Wout_W + 2ll*770*770, 770, Wout_b + 2*770, v2, 770, 770, 0);

    final_k<<<Bq, 256, 0, stream>>>(v2, out_W, out_b, out);

    (void)in_sizes; (void)n_in; (void)out_size; (void)ws_size;
    (void)av; (void)pv; (void)avU_bf; (void)qbuf; (void)csum;
    (void)scoreC; (void)scoreP; (void)h; (void)multi; (void)avp;
    (void)bufU_all; (void)c1; (void)cf; (void)pf;
}